// Round 2
// baseline (4305.028 us; speedup 1.0000x reference)
//
#include <hip/hip_runtime.h>
#include <math.h>

#define NN 50000
#define EE 800000
#define DD 256
#define HH 256
#define LL 64
#define EP (EE + NN)   // edges + self loops

__device__ __forceinline__ float lrelu(float x) { return x > 0.f ? x : 0.2f * x; }
__device__ __forceinline__ float gelu_exact(float x) {
    return 0.5f * x * (1.f + erff(x * 0.70710678118654752f));
}

// ---------------- dense: C[M,Nc] = A[M,K] @ W[K,Nc] (+bias) ----------------
__global__ __launch_bounds__(256) void mm_kernel(const float* __restrict__ A,
                                                 const float* __restrict__ W,
                                                 const float* __restrict__ bias,
                                                 float* __restrict__ C,
                                                 int M, int K, int Nc) {
    __shared__ float As[16][64];
    __shared__ float Bs[16][64];
    const int tid = threadIdx.x;
    const int tr = tid >> 4;         // 0..15
    const int tc = tid & 15;         // 0..15
    const int row0 = blockIdx.y * 64;
    const int col0 = blockIdx.x * 64;
    float acc[4][4] = {};

    const int arow = tid >> 2;       // 0..63
    const int ak = (tid & 3) << 2;   // 0,4,8,12
    const int bk = tid >> 4;         // 0..15
    const int bc = (tid & 15) << 2;  // 0..60

    for (int k0 = 0; k0 < K; k0 += 16) {
        float4 av = make_float4(0.f, 0.f, 0.f, 0.f);
        if (row0 + arow < M)
            av = *(const float4*)(A + (size_t)(row0 + arow) * K + k0 + ak);
        As[ak + 0][arow] = av.x;
        As[ak + 1][arow] = av.y;
        As[ak + 2][arow] = av.z;
        As[ak + 3][arow] = av.w;
        *(float4*)(&Bs[bk][bc]) = *(const float4*)(W + (size_t)(k0 + bk) * Nc + col0 + bc);
        __syncthreads();
#pragma unroll
        for (int kk = 0; kk < 16; kk++) {
            float4 a4 = *(const float4*)(&As[kk][tr << 2]);
            float4 b4 = *(const float4*)(&Bs[kk][tc << 2]);
            float a[4] = {a4.x, a4.y, a4.z, a4.w};
            float b[4] = {b4.x, b4.y, b4.z, b4.w};
#pragma unroll
            for (int i = 0; i < 4; i++)
#pragma unroll
                for (int j = 0; j < 4; j++) acc[i][j] = fmaf(a[i], b[j], acc[i][j]);
        }
        __syncthreads();
    }
#pragma unroll
    for (int i = 0; i < 4; i++) {
        int r = row0 + (tr << 2) + i;
        if (r < M) {
#pragma unroll
            for (int j = 0; j < 4; j++) {
                int c = col0 + (tc << 2) + j;
                float v = acc[i][j];
                if (bias) v += bias[c];
                C[(size_t)r * Nc + c] = v;
            }
        }
    }
}

// ---------------- CSR build ----------------
__global__ void hist_kernel(const int* __restrict__ dst, int* __restrict__ deg) {
    int e = blockIdx.x * blockDim.x + threadIdx.x;
    if (e >= EP) return;
    int d = (e < EE) ? dst[e] : (e - EE);
    atomicAdd(&deg[d], 1);
}

__global__ void scan_kernel(const int* __restrict__ deg, int* __restrict__ row_ptr,
                            int* __restrict__ wptr) {
    int lane = threadIdx.x;  // single block of 64
    int carry = 0;
    for (int base = 0; base < NN; base += 64) {
        int i = base + lane;
        int v = (i < NN) ? deg[i] : 0;
        int x = v;
#pragma unroll
        for (int off = 1; off < 64; off <<= 1) {
            int y = __shfl_up(x, off);
            if (lane >= off) x += y;
        }
        if (i < NN) {
            int excl = carry + x - v;
            row_ptr[i] = excl;
            wptr[i] = excl;
        }
        carry += __shfl(x, 63);
    }
    if (lane == 0) row_ptr[NN] = carry;
}

__global__ void scatter_kernel(const int* __restrict__ src, const int* __restrict__ dst,
                               int* __restrict__ wptr, int* __restrict__ col) {
    int e = blockIdx.x * blockDim.x + threadIdx.x;
    if (e >= EP) return;
    int s, d;
    if (e < EE) { s = src[e]; d = dst[e]; } else { s = d = e - EE; }
    int pos = atomicAdd(&wptr[d], 1);
    col[pos] = s;
}

// ---------------- GATv2 edge phase: one wave per node ----------------
// pass 1: online softmax stats (m, sum) per node
__global__ __launch_bounds__(256) void gat_pass1(const float* __restrict__ xl,
                                                 const float* __restrict__ xr,
                                                 const int* __restrict__ row_ptr,
                                                 const int* __restrict__ col,
                                                 const float* __restrict__ att,
                                                 float* __restrict__ node_m,
                                                 float* __restrict__ node_s) {
    int wid = (blockIdx.x * blockDim.x + threadIdx.x) >> 6;
    int lane = threadIdx.x & 63;
    if (wid >= NN) return;
    int start = row_ptr[wid], end = row_ptr[wid + 1];
    float4 xrv = *(const float4*)(xr + (size_t)wid * HH + lane * 4);
    float4 at  = *(const float4*)(att + lane * 4);
    float m = -1e30f, ssum = 0.f;
    for (int e = start; e < end; e++) {
        int s = col[e];
        float4 xv = *(const float4*)(xl + (size_t)s * HH + lane * 4);
        float p = lrelu(xv.x + xrv.x) * at.x + lrelu(xv.y + xrv.y) * at.y +
                  lrelu(xv.z + xrv.z) * at.z + lrelu(xv.w + xrv.w) * at.w;
#pragma unroll
        for (int off = 32; off; off >>= 1) p += __shfl_xor(p, off);
        float mn = fmaxf(m, p);
        ssum = ssum * __expf(m - mn) + __expf(p - mn);
        m = mn;
    }
    if (lane == 0) { node_m[wid] = m; node_s[wid] = ssum; }
}

// pass 2: recompute score, accumulate alpha * h_src, + bias, optional gelu
__global__ __launch_bounds__(256) void gat_pass2(const float* __restrict__ xl,
                                                 const float* __restrict__ xr,
                                                 const int* __restrict__ row_ptr,
                                                 const int* __restrict__ col,
                                                 const float* __restrict__ att,
                                                 const float* __restrict__ node_m,
                                                 const float* __restrict__ node_s,
                                                 const float* __restrict__ bias,
                                                 float* __restrict__ out,
                                                 int do_gelu) {
    int wid = (blockIdx.x * blockDim.x + threadIdx.x) >> 6;
    int lane = threadIdx.x & 63;
    if (wid >= NN) return;
    int start = row_ptr[wid], end = row_ptr[wid + 1];
    float4 xrv = *(const float4*)(xr + (size_t)wid * HH + lane * 4);
    float4 at  = *(const float4*)(att + lane * 4);
    float m = node_m[wid];
    float inv_s = 1.f / node_s[wid];
    float4 acc = make_float4(0.f, 0.f, 0.f, 0.f);
    for (int e = start; e < end; e++) {
        int s = col[e];
        float4 xv = *(const float4*)(xl + (size_t)s * HH + lane * 4);
        float p = lrelu(xv.x + xrv.x) * at.x + lrelu(xv.y + xrv.y) * at.y +
                  lrelu(xv.z + xrv.z) * at.z + lrelu(xv.w + xrv.w) * at.w;
#pragma unroll
        for (int off = 32; off; off >>= 1) p += __shfl_xor(p, off);
        float alpha = __expf(p - m) * inv_s;
        acc.x = fmaf(alpha, xv.x, acc.x);
        acc.y = fmaf(alpha, xv.y, acc.y);
        acc.z = fmaf(alpha, xv.z, acc.z);
        acc.w = fmaf(alpha, xv.w, acc.w);
    }
    float4 bv = *(const float4*)(bias + lane * 4);
    acc.x += bv.x; acc.y += bv.y; acc.z += bv.z; acc.w += bv.w;
    if (do_gelu) {
        acc.x = gelu_exact(acc.x); acc.y = gelu_exact(acc.y);
        acc.z = gelu_exact(acc.z); acc.w = gelu_exact(acc.w);
    }
    *(float4*)(out + (size_t)wid * HH + lane * 4) = acc;
}

// ---------------- mu/logstd/z elementwise ----------------
__global__ void z_kernel(float* __restrict__ mu, float* __restrict__ lstd,
                         const float* __restrict__ eps, float* __restrict__ z) {
    int i = blockIdx.x * blockDim.x + threadIdx.x;
    if (i >= NN * LL) return;
    float ls = fminf(lstd[i], 10.f);
    lstd[i] = ls;
    z[i] = fmaf(eps[i], __expf(ls), mu[i]);
}

extern "C" void kernel_launch(void* const* d_in, const int* in_sizes, int n_in,
                              void* d_out, int out_size, void* d_ws, size_t ws_size,
                              hipStream_t stream) {
    const float* x       = (const float*)d_in[0];
    const int*   ei      = (const int*)d_in[1];
    const float* eps     = (const float*)d_in[2];
    const float* enc_Wl  = (const float*)d_in[3];
    const float* enc_Wr  = (const float*)d_in[4];
    const float* enc_att = (const float*)d_in[5];
    const float* enc_b   = (const float*)d_in[6];
    const float* mu_W    = (const float*)d_in[7];
    const float* mu_b    = (const float*)d_in[8];
    const float* ls_W    = (const float*)d_in[9];
    const float* ls_b    = (const float*)d_in[10];
    const float* dec0_Wl = (const float*)d_in[11];
    const float* dec0_Wr = (const float*)d_in[12];
    const float* dec0_att= (const float*)d_in[13];
    const float* dec0_b  = (const float*)d_in[14];
    const float* dec_Wl  = (const float*)d_in[15];
    const float* dec_Wr  = (const float*)d_in[16];
    const float* dec_att = (const float*)d_in[17];
    const float* dec_b   = (const float*)d_in[18];
    const float* out_W   = (const float*)d_in[19];
    const float* out_b   = (const float*)d_in[20];

    const int* esrc = ei;
    const int* edst = ei + EE;

    float* out_f = (float*)d_out;
    float* xrec = out_f;
    float* z    = out_f + (size_t)NN * DD;
    float* mu   = z + (size_t)NN * LL;
    float* lstd = mu + (size_t)NN * LL;

    float* wsf = (float*)d_ws;
    float* bufA  = wsf;                          // N*H
    float* bufXL = wsf + (size_t)NN * HH;        // N*H
    float* bufXR = wsf + 2 * (size_t)NN * HH;    // N*H
    int* deg     = (int*)(wsf + 3 * (size_t)NN * HH);
    int* row_ptr = deg + NN;
    int* wptr    = row_ptr + NN + 1;
    int* col     = wptr + NN;
    float* node_m = (float*)(col + EP);
    float* node_s = node_m + NN;

    const int eb = (EP + 255) / 256;
    const int nb = (NN * 64 + 255) / 256;
    dim3 mmg(HH / 64, (NN + 63) / 64);
    dim3 mmg_small(LL / 64, (NN + 63) / 64);

    // ---- CSR build (per call; harness replays the whole graph) ----
    hipMemsetAsync(deg, 0, (size_t)NN * sizeof(int), stream);
    hist_kernel<<<eb, 256, 0, stream>>>(edst, deg);
    scan_kernel<<<1, 64, 0, stream>>>(deg, row_ptr, wptr);
    scatter_kernel<<<eb, 256, 0, stream>>>(esrc, edst, wptr, col);

    // ---- encoder: 4 GATv2 + gelu ----
    for (int l = 0; l < 4; l++) {
        const float* in = (l == 0) ? x : bufA;
        mm_kernel<<<mmg, 256, 0, stream>>>(in, enc_Wl + (size_t)l * DD * HH, nullptr,
                                           bufXL, NN, DD, HH);
        mm_kernel<<<mmg, 256, 0, stream>>>(in, enc_Wr + (size_t)l * DD * HH, nullptr,
                                           bufXR, NN, DD, HH);
        gat_pass1<<<nb, 256, 0, stream>>>(bufXL, bufXR, row_ptr, col,
                                          enc_att + (size_t)l * HH, node_m, node_s);
        gat_pass2<<<nb, 256, 0, stream>>>(bufXL, bufXR, row_ptr, col,
                                          enc_att + (size_t)l * HH, node_m, node_s,
                                          enc_b + (size_t)l * HH, bufA, 1);
    }

    // ---- mu / logstd / z ----
    mm_kernel<<<mmg_small, 256, 0, stream>>>(bufA, mu_W, mu_b, mu, NN, HH, LL);
    mm_kernel<<<mmg_small, 256, 0, stream>>>(bufA, ls_W, ls_b, lstd, NN, HH, LL);
    z_kernel<<<(NN * LL + 255) / 256, 256, 0, stream>>>(mu, lstd, eps, z);

    // ---- decoder: 4 GATv2 + gelu ----
    for (int l = 0; l < 4; l++) {
        const float* in; const float* Wl; const float* Wr; const float* at; const float* bb;
        int K;
        if (l == 0) {
            in = z; Wl = dec0_Wl; Wr = dec0_Wr; at = dec0_att; bb = dec0_b; K = LL;
        } else {
            in = bufA;
            Wl = dec_Wl + (size_t)(l - 1) * HH * HH;
            Wr = dec_Wr + (size_t)(l - 1) * HH * HH;
            at = dec_att + (size_t)(l - 1) * HH;
            bb = dec_b + (size_t)(l - 1) * HH;
            K = HH;
        }
        mm_kernel<<<mmg, 256, 0, stream>>>(in, Wl, nullptr, bufXL, NN, K, HH);
        mm_kernel<<<mmg, 256, 0, stream>>>(in, Wr, nullptr, bufXR, NN, K, HH);
        gat_pass1<<<nb, 256, 0, stream>>>(bufXL, bufXR, row_ptr, col, at, node_m, node_s);
        gat_pass2<<<nb, 256, 0, stream>>>(bufXL, bufXR, row_ptr, col, at, node_m, node_s,
                                          bb, bufA, 1);
    }

    // ---- output projection ----
    mm_kernel<<<mmg, 256, 0, stream>>>(bufA, out_W, out_b, xrec, NN, HH, DD);
}

// Round 3
// 2957.200 us; speedup vs baseline: 1.4558x; 1.4558x over previous
//
#include <hip/hip_runtime.h>
#include <math.h>

#define NN 50000
#define EE 800000
#define DD 256
#define HH 256
#define LL 64
#define EP (EE + NN)          // edges + self loops
#define MP 50048              // 391 * 128, padded row count
#define NB2 ((NN + 255) / 256)

typedef __attribute__((ext_vector_type(8))) short short8;
typedef __attribute__((ext_vector_type(4))) float f32x4;

__device__ __forceinline__ float lrelu(float x) { return x > 0.f ? x : 0.2f * x; }
__device__ __forceinline__ float gelu_exact(float x) {
    return 0.5f * x * (1.f + erff(x * 0.70710678118654752f));
}
__device__ __forceinline__ ushort f2bf(float x) {
    union { float f; unsigned u; } v; v.f = x;
    unsigned r = v.u + 0x7fff + ((v.u >> 16) & 1);
    return (ushort)(r >> 16);
}
__device__ __forceinline__ float bf2f(ushort h) {
    union { float f; unsigned u; } v; v.u = ((unsigned)h) << 16;
    return v.f;
}

// ================= split-bf16 MFMA GEMM =================
// C[M,Nc] = A[M,K] @ W[K,Nc] + bias, where A given as hi/lo bf16 [MP][K]
// and W given transposed as WT hi/lo bf16 [Nc][K].
// Tile 128x128, BK=32, 4 waves (2x2), per wave 4x4 frags of 16x16x32.
__global__ __launch_bounds__(256) void mm_bf16(const ushort* __restrict__ Ah,
                                               const ushort* __restrict__ Al,
                                               const ushort* __restrict__ Bh,
                                               const ushort* __restrict__ Bl,
                                               const float* __restrict__ bias,
                                               float* __restrict__ C,
                                               int M, int K, int Nc) {
    __shared__ ushort As_h[128][40];
    __shared__ ushort As_l[128][40];
    __shared__ ushort Bs_h[128][40];
    __shared__ ushort Bs_l[128][40];
    const int tid = threadIdx.x;
    const int lane = tid & 63;
    const int wid = tid >> 6;
    const int wr = wid >> 1, wc = wid & 1;
    const int row0 = blockIdx.y * 128;
    const int col0 = blockIdx.x * 128;
    const int srow = tid >> 2;       // 0..63
    const int sk = (tid & 3) << 3;   // 0,8,16,24
    const int fr = lane & 15;
    const int kg = (lane >> 4) << 3; // 0,8,16,24

    f32x4 acc[4][4] = {};

    for (int k0 = 0; k0 < K; k0 += 32) {
#pragma unroll
        for (int h = 0; h < 2; h++) {
            int r = srow + h * 64;
            size_t ga = (size_t)(row0 + r) * K + k0 + sk;
            *(int4*)(&As_h[r][sk]) = *(const int4*)(Ah + ga);
            *(int4*)(&As_l[r][sk]) = *(const int4*)(Al + ga);
            int c = col0 + r;
            int4 bh4 = {0, 0, 0, 0}, bl4 = {0, 0, 0, 0};
            if (c < Nc) {
                size_t gb = (size_t)c * K + k0 + sk;
                bh4 = *(const int4*)(Bh + gb);
                bl4 = *(const int4*)(Bl + gb);
            }
            *(int4*)(&Bs_h[r][sk]) = bh4;
            *(int4*)(&Bs_l[r][sk]) = bl4;
        }
        __syncthreads();
        short8 ah[4], al[4], bh[4], bl[4];
#pragma unroll
        for (int m = 0; m < 4; m++) {
            ah[m] = *(const short8*)&As_h[wr * 64 + m * 16 + fr][kg];
            al[m] = *(const short8*)&As_l[wr * 64 + m * 16 + fr][kg];
        }
#pragma unroll
        for (int n = 0; n < 4; n++) {
            bh[n] = *(const short8*)&Bs_h[wc * 64 + n * 16 + fr][kg];
            bl[n] = *(const short8*)&Bs_l[wc * 64 + n * 16 + fr][kg];
        }
#pragma unroll
        for (int m = 0; m < 4; m++)
#pragma unroll
            for (int n = 0; n < 4; n++) {
                acc[m][n] = __builtin_amdgcn_mfma_f32_16x16x32_bf16(ah[m], bh[n], acc[m][n], 0, 0, 0);
                acc[m][n] = __builtin_amdgcn_mfma_f32_16x16x32_bf16(ah[m], bl[n], acc[m][n], 0, 0, 0);
                acc[m][n] = __builtin_amdgcn_mfma_f32_16x16x32_bf16(al[m], bh[n], acc[m][n], 0, 0, 0);
            }
        __syncthreads();
    }
    // C/D layout: col = lane&15, row = (lane>>4)*4 + r  [verified m89/m91]
#pragma unroll
    for (int m = 0; m < 4; m++) {
        int rbase = row0 + wr * 64 + m * 16 + (lane >> 4) * 4;
#pragma unroll
        for (int n = 0; n < 4; n++) {
            int c = col0 + wc * 64 + n * 16 + fr;
            if (c < Nc) {
                float bv = bias ? bias[c] : 0.f;
#pragma unroll
                for (int r = 0; r < 4; r++) {
                    int rr = rbase + r;
                    if (rr < M) C[(size_t)rr * Nc + c] = acc[m][n][r] + bv;
                }
            }
        }
    }
}

// ================= weight transpose + hi/lo split =================
struct WDesc { const float* W; ushort* Th; ushort* Tl; int K; int N; };
struct WPack { WDesc d[19]; };

__global__ void wconv_kernel(WPack p) {
    WDesc w = p.d[blockIdx.y];
    int idx = blockIdx.x * 256 + threadIdx.x;
    int total = w.K * w.N;
    if (idx >= total) return;
    int n = idx / w.K, k = idx - n * w.K;
    float v = w.W[(size_t)k * w.N + n];
    ushort hi = f2bf(v);
    w.Th[idx] = hi;
    w.Tl[idx] = f2bf(v - bf2f(hi));
}

// ================= fp32 -> hi/lo bf16 conversion =================
__global__ void conv_kernel(const float* __restrict__ in, ushort* __restrict__ oh,
                            ushort* __restrict__ ol, int total4) {
    int i = blockIdx.x * 256 + threadIdx.x;
    if (i >= total4) return;
    float4 v = *(const float4*)(in + (size_t)i * 4);
    ushort4 h, l;
    h.x = f2bf(v.x); l.x = f2bf(v.x - bf2f(h.x));
    h.y = f2bf(v.y); l.y = f2bf(v.y - bf2f(h.y));
    h.z = f2bf(v.z); l.z = f2bf(v.z - bf2f(h.z));
    h.w = f2bf(v.w); l.w = f2bf(v.w - bf2f(h.w));
    *(ushort4*)(oh + (size_t)i * 4) = h;
    *(ushort4*)(ol + (size_t)i * 4) = l;
}

// ================= CSR build =================
__global__ void hist_kernel(const int* __restrict__ dst, int* __restrict__ deg) {
    int e = blockIdx.x * blockDim.x + threadIdx.x;
    if (e >= EP) return;
    int d = (e < EE) ? dst[e] : (e - EE);
    atomicAdd(&deg[d], 1);
}

__global__ void bsum_kernel(const int* __restrict__ deg, int* __restrict__ bsum) {
    __shared__ int wsum[4];
    int i = blockIdx.x * 256 + threadIdx.x;
    int v = (i < NN) ? deg[i] : 0;
#pragma unroll
    for (int off = 32; off; off >>= 1) v += __shfl_xor(v, off);
    if ((threadIdx.x & 63) == 0) wsum[threadIdx.x >> 6] = v;
    __syncthreads();
    if (threadIdx.x == 0) bsum[blockIdx.x] = wsum[0] + wsum[1] + wsum[2] + wsum[3];
}

__global__ void bscan_kernel(const int* __restrict__ bsum, int* __restrict__ boff,
                             int* __restrict__ row_last, int nb) {
    int lane = threadIdx.x;  // 64 threads, 1 block
    int carry = 0;
    for (int base = 0; base < nb; base += 64) {
        int i = base + lane;
        int v = (i < nb) ? bsum[i] : 0;
        int x = v;
#pragma unroll
        for (int off = 1; off < 64; off <<= 1) {
            int y = __shfl_up(x, off);
            if (lane >= off) x += y;
        }
        if (i < nb) boff[i] = carry + x - v;
        carry += __shfl(x, 63);
    }
    if (lane == 0) *row_last = carry;
}

__global__ void blockscan_kernel(const int* __restrict__ deg, const int* __restrict__ boff,
                                 int* __restrict__ row_ptr, int* __restrict__ wptr) {
    __shared__ int wsum[4];
    int i = blockIdx.x * 256 + threadIdx.x;
    int v = (i < NN) ? deg[i] : 0;
    int lane = threadIdx.x & 63, w = threadIdx.x >> 6;
    int x = v;
#pragma unroll
    for (int off = 1; off < 64; off <<= 1) {
        int y = __shfl_up(x, off);
        if (lane >= off) x += y;
    }
    if (lane == 63) wsum[w] = x;
    __syncthreads();
    int wo = 0;
    for (int j = 0; j < w; j++) wo += wsum[j];
    if (i < NN) {
        int excl = boff[blockIdx.x] + wo + x - v;
        row_ptr[i] = excl;
        wptr[i] = excl;
    }
}

__global__ void scatter_kernel(const int* __restrict__ src, const int* __restrict__ dst,
                               int* __restrict__ wptr, int* __restrict__ col) {
    int e = blockIdx.x * blockDim.x + threadIdx.x;
    if (e >= EP) return;
    int s, d;
    if (e < EE) { s = src[e]; d = dst[e]; } else { s = d = e - EE; }
    int pos = atomicAdd(&wptr[d], 1);
    col[pos] = s;
}

// ================= fused GATv2 edge phase (flash-style online softmax) ====
// one wave per node; writes hi/lo bf16 of gelu(agg + bias) for next GEMM
__global__ __launch_bounds__(256) void gat_fused(const float* __restrict__ xl,
                                                 const float* __restrict__ xr,
                                                 const int* __restrict__ row_ptr,
                                                 const int* __restrict__ col,
                                                 const float* __restrict__ att,
                                                 const float* __restrict__ bias,
                                                 ushort* __restrict__ outH,
                                                 ushort* __restrict__ outL) {
    int wid = (blockIdx.x * blockDim.x + threadIdx.x) >> 6;
    int lane = threadIdx.x & 63;
    if (wid >= NN) return;
    int start = row_ptr[wid], end = row_ptr[wid + 1];
    float4 xrv = *(const float4*)(xr + (size_t)wid * HH + lane * 4);
    float4 at  = *(const float4*)(att + lane * 4);
    float m = -1e30f, ssum = 0.f;
    float4 acc = make_float4(0.f, 0.f, 0.f, 0.f);
    for (int e = start; e < end; e++) {
        int s = col[e];
        float4 xv = *(const float4*)(xl + (size_t)s * HH + lane * 4);
        float p = lrelu(xv.x + xrv.x) * at.x + lrelu(xv.y + xrv.y) * at.y +
                  lrelu(xv.z + xrv.z) * at.z + lrelu(xv.w + xrv.w) * at.w;
#pragma unroll
        for (int off = 32; off; off >>= 1) p += __shfl_xor(p, off);
        if (p <= m) {                       // wave-uniform branch
            float w = __expf(p - m);
            ssum += w;
            acc.x = fmaf(w, xv.x, acc.x);
            acc.y = fmaf(w, xv.y, acc.y);
            acc.z = fmaf(w, xv.z, acc.z);
            acc.w = fmaf(w, xv.w, acc.w);
        } else {
            float sc = __expf(m - p);       // 0 on first edge
            ssum = fmaf(ssum, sc, 1.f);
            acc.x = fmaf(acc.x, sc, xv.x);
            acc.y = fmaf(acc.y, sc, xv.y);
            acc.z = fmaf(acc.z, sc, xv.z);
            acc.w = fmaf(acc.w, sc, xv.w);
            m = p;
        }
    }
    float inv = 1.f / ssum;
    float4 bv = *(const float4*)(bias + lane * 4);
    float o0 = gelu_exact(fmaf(acc.x, inv, bv.x));
    float o1 = gelu_exact(fmaf(acc.y, inv, bv.y));
    float o2 = gelu_exact(fmaf(acc.z, inv, bv.z));
    float o3 = gelu_exact(fmaf(acc.w, inv, bv.w));
    ushort4 h, l;
    h.x = f2bf(o0); l.x = f2bf(o0 - bf2f(h.x));
    h.y = f2bf(o1); l.y = f2bf(o1 - bf2f(h.y));
    h.z = f2bf(o2); l.z = f2bf(o2 - bf2f(h.z));
    h.w = f2bf(o3); l.w = f2bf(o3 - bf2f(h.w));
    size_t o = (size_t)wid * HH + lane * 4;
    *(ushort4*)(outH + o) = h;
    *(ushort4*)(outL + o) = l;
}

// ================= mu/logstd/z elementwise =================
__global__ void z_kernel(float* __restrict__ mu, float* __restrict__ lstd,
                         const float* __restrict__ eps, float* __restrict__ z) {
    int i = blockIdx.x * blockDim.x + threadIdx.x;
    if (i >= NN * LL) return;
    float ls = fminf(lstd[i], 10.f);
    lstd[i] = ls;
    z[i] = fmaf(eps[i], __expf(ls), mu[i]);
}

extern "C" void kernel_launch(void* const* d_in, const int* in_sizes, int n_in,
                              void* d_out, int out_size, void* d_ws, size_t ws_size,
                              hipStream_t stream) {
    const float* x       = (const float*)d_in[0];
    const int*   ei      = (const int*)d_in[1];
    const float* eps     = (const float*)d_in[2];
    const float* enc_Wl  = (const float*)d_in[3];
    const float* enc_Wr  = (const float*)d_in[4];
    const float* enc_att = (const float*)d_in[5];
    const float* enc_b   = (const float*)d_in[6];
    const float* mu_W    = (const float*)d_in[7];
    const float* mu_b    = (const float*)d_in[8];
    const float* ls_W    = (const float*)d_in[9];
    const float* ls_b    = (const float*)d_in[10];
    const float* dec0_Wl = (const float*)d_in[11];
    const float* dec0_Wr = (const float*)d_in[12];
    const float* dec0_att= (const float*)d_in[13];
    const float* dec0_b  = (const float*)d_in[14];
    const float* dec_Wl  = (const float*)d_in[15];
    const float* dec_Wr  = (const float*)d_in[16];
    const float* dec_att = (const float*)d_in[17];
    const float* dec_b   = (const float*)d_in[18];
    const float* out_W   = (const float*)d_in[19];
    const float* out_b   = (const float*)d_in[20];

    const int* esrc = ei;
    const int* edst = ei + EE;

    float* out_f = (float*)d_out;
    float* xrec = out_f;
    float* z    = out_f + (size_t)NN * DD;
    float* mu   = z + (size_t)NN * LL;
    float* lstd = mu + (size_t)NN * LL;

    // ---- workspace layout ----
    float* wsf = (float*)d_ws;
    float* xlb = wsf;                               // MP*256 f32
    float* xrb = xlb + (size_t)MP * 256;            // MP*256 f32
    ushort* Ah = (ushort*)(xrb + (size_t)MP * 256); // MP*256 bf16
    ushort* Al = Ah + (size_t)MP * 256;
    ushort* Th = Al + (size_t)MP * 256;             // 1,048,576 bf16
    ushort* Tl = Th + 1048576;
    int* deg     = (int*)(Tl + 1048576);
    int* row_ptr = deg + NN;
    int* wptr    = row_ptr + NN + 1;
    int* col     = wptr + NN;
    int* bsum    = col + EP;
    int* boff    = bsum + 256;

    // weight-transpose descriptor pack
    WPack p;
    size_t off = 0;
    auto add = [&](int i, const float* W, int K, int N) {
        p.d[i] = {W, Th + off, Tl + off, K, N};
        off += (size_t)K * N;
    };
    for (int l = 0; l < 4; l++) add(l,     enc_Wl + (size_t)l * DD * HH, DD, HH);
    for (int l = 0; l < 4; l++) add(4 + l, enc_Wr + (size_t)l * DD * HH, DD, HH);
    add(8, dec0_Wl, LL, HH);
    add(9, dec0_Wr, LL, HH);
    for (int l = 0; l < 3; l++) add(10 + l, dec_Wl + (size_t)l * HH * HH, HH, HH);
    for (int l = 0; l < 3; l++) add(13 + l, dec_Wr + (size_t)l * HH * HH, HH, HH);
    add(16, out_W, HH, DD);
    add(17, mu_W, HH, LL);
    add(18, ls_W, HH, LL);

    const int eb = (EP + 255) / 256;
    const int nb = (NN * 64 + 255) / 256;
    dim3 mmg(2, MP / 128);        // Nc=256
    dim3 mmg_small(1, MP / 128);  // Nc=64

    // ---- weight conversion + CSR build ----
    wconv_kernel<<<dim3(256, 19), 256, 0, stream>>>(p);
    hipMemsetAsync(deg, 0, (size_t)NN * sizeof(int), stream);
    hist_kernel<<<eb, 256, 0, stream>>>(edst, deg);
    bsum_kernel<<<NB2, 256, 0, stream>>>(deg, bsum);
    bscan_kernel<<<1, 64, 0, stream>>>(bsum, boff, row_ptr + NN, NB2);
    blockscan_kernel<<<NB2, 256, 0, stream>>>(deg, boff, row_ptr, wptr);
    scatter_kernel<<<eb, 256, 0, stream>>>(esrc, edst, wptr, col);

    // ---- x -> hi/lo ----
    conv_kernel<<<(NN * 64), 256, 0, stream>>>(x, Ah, Al, NN * 64);  // NN*256/4 = NN*64

    // ---- encoder ----
    for (int l = 0; l < 4; l++) {
        mm_bf16<<<mmg, 256, 0, stream>>>(Ah, Al, p.d[l].Th, p.d[l].Tl, nullptr,
                                         xlb, NN, DD, HH);
        mm_bf16<<<mmg, 256, 0, stream>>>(Ah, Al, p.d[4 + l].Th, p.d[4 + l].Tl, nullptr,
                                         xrb, NN, DD, HH);
        gat_fused<<<nb, 256, 0, stream>>>(xlb, xrb, row_ptr, col,
                                          enc_att + (size_t)l * HH,
                                          enc_b + (size_t)l * HH, Ah, Al);
    }

    // ---- mu / logstd / z ----
    mm_bf16<<<mmg_small, 256, 0, stream>>>(Ah, Al, p.d[17].Th, p.d[17].Tl, mu_b,
                                           mu, NN, HH, LL);
    mm_bf16<<<mmg_small, 256, 0, stream>>>(Ah, Al, p.d[18].Th, p.d[18].Tl, ls_b,
                                           lstd, NN, HH, LL);
    z_kernel<<<(NN * LL + 255) / 256, 256, 0, stream>>>(mu, lstd, eps, z);
    conv_kernel<<<(NN * 16), 256, 0, stream>>>(z, Ah, Al, NN * 16);  // NN*64/4

    // ---- decoder ----
    for (int l = 0; l < 4; l++) {
        const ushort *TlH, *TlL, *TrH, *TrL;
        const float *at, *bb;
        int K;
        if (l == 0) {
            TlH = p.d[8].Th; TlL = p.d[8].Tl; TrH = p.d[9].Th; TrL = p.d[9].Tl;
            at = dec0_att; bb = dec0_b; K = LL;
        } else {
            TlH = p.d[10 + l - 1].Th; TlL = p.d[10 + l - 1].Tl;
            TrH = p.d[13 + l - 1].Th; TrL = p.d[13 + l - 1].Tl;
            at = dec_att + (size_t)(l - 1) * HH;
            bb = dec_b + (size_t)(l - 1) * HH;
            K = HH;
        }
        mm_bf16<<<mmg, 256, 0, stream>>>(Ah, Al, TlH, TlL, nullptr, xlb, NN, K, HH);
        mm_bf16<<<mmg, 256, 0, stream>>>(Ah, Al, TrH, TrL, nullptr, xrb, NN, K, HH);
        gat_fused<<<nb, 256, 0, stream>>>(xlb, xrb, row_ptr, col, at, bb, Ah, Al);
    }

    // ---- output projection ----
    mm_bf16<<<mmg, 256, 0, stream>>>(Ah, Al, p.d[16].Th, p.d[16].Tl, out_b,
                                     xrec, NN, HH, DD);
}

// Round 4
// 1925.723 us; speedup vs baseline: 2.2355x; 1.5356x over previous
//
#include <hip/hip_runtime.h>
#include <math.h>

#define NN 50000
#define EE 800000
#define DD 256
#define HH 256
#define LL 64
#define EP (EE + NN)          // edges + self loops
#define MP 50048              // 391 * 128, padded row count
#define NB2 ((NN + 255) / 256)
#define XLR 512               // fused xl|xr row stride

typedef __attribute__((ext_vector_type(8))) short short8;
typedef __attribute__((ext_vector_type(4))) float f32x4;

__device__ __forceinline__ float lrelu(float x) { return x > 0.f ? x : 0.2f * x; }
__device__ __forceinline__ float gelu_exact(float x) {
    return 0.5f * x * (1.f + erff(x * 0.70710678118654752f));
}
__device__ __forceinline__ ushort f2bf(float x) {
    union { float f; unsigned u; } v; v.f = x;
    unsigned r = v.u + 0x7fff + ((v.u >> 16) & 1);
    return (ushort)(r >> 16);
}
__device__ __forceinline__ float bf2f(ushort h) {
    union { float f; unsigned u; } v; v.u = ((unsigned)h) << 16;
    return v.f;
}

// ================= split-bf16 MFMA GEMM =================
// C[M,Nc] = A[M,K] @ B^T + bias, A as hi/lo bf16 [MP][K], B as [Nc][K] hi/lo.
// Tile 128x128, BK=32, 4 waves (2x2), per wave 4x4 frags of 16x16x32.
__global__ __launch_bounds__(256) void mm_bf16(const ushort* __restrict__ Ah,
                                               const ushort* __restrict__ Al,
                                               const ushort* __restrict__ Bh,
                                               const ushort* __restrict__ Bl,
                                               const float* __restrict__ bias,
                                               float* __restrict__ C,
                                               int M, int K, int Nc) {
    __shared__ ushort As_h[128][40];
    __shared__ ushort As_l[128][40];
    __shared__ ushort Bs_h[128][40];
    __shared__ ushort Bs_l[128][40];
    const int tid = threadIdx.x;
    const int lane = tid & 63;
    const int wid = tid >> 6;
    const int wr = wid >> 1, wc = wid & 1;
    const int row0 = blockIdx.y * 128;
    const int col0 = blockIdx.x * 128;
    const int srow = tid >> 2;       // 0..63
    const int sk = (tid & 3) << 3;   // 0,8,16,24
    const int fr = lane & 15;
    const int kg = (lane >> 4) << 3; // 0,8,16,24

    f32x4 acc[4][4] = {};

    for (int k0 = 0; k0 < K; k0 += 32) {
#pragma unroll
        for (int h = 0; h < 2; h++) {
            int r = srow + h * 64;
            size_t ga = (size_t)(row0 + r) * K + k0 + sk;
            *(int4*)(&As_h[r][sk]) = *(const int4*)(Ah + ga);
            *(int4*)(&As_l[r][sk]) = *(const int4*)(Al + ga);
            int c = col0 + r;
            int4 bh4 = {0, 0, 0, 0}, bl4 = {0, 0, 0, 0};
            if (c < Nc) {
                size_t gb = (size_t)c * K + k0 + sk;
                bh4 = *(const int4*)(Bh + gb);
                bl4 = *(const int4*)(Bl + gb);
            }
            *(int4*)(&Bs_h[r][sk]) = bh4;
            *(int4*)(&Bs_l[r][sk]) = bl4;
        }
        __syncthreads();
        short8 ah[4], al[4], bh[4], bl[4];
#pragma unroll
        for (int m = 0; m < 4; m++) {
            ah[m] = *(const short8*)&As_h[wr * 64 + m * 16 + fr][kg];
            al[m] = *(const short8*)&As_l[wr * 64 + m * 16 + fr][kg];
        }
#pragma unroll
        for (int n = 0; n < 4; n++) {
            bh[n] = *(const short8*)&Bs_h[wc * 64 + n * 16 + fr][kg];
            bl[n] = *(const short8*)&Bs_l[wc * 64 + n * 16 + fr][kg];
        }
#pragma unroll
        for (int m = 0; m < 4; m++)
#pragma unroll
            for (int n = 0; n < 4; n++) {
                acc[m][n] = __builtin_amdgcn_mfma_f32_16x16x32_bf16(ah[m], bh[n], acc[m][n], 0, 0, 0);
                acc[m][n] = __builtin_amdgcn_mfma_f32_16x16x32_bf16(ah[m], bl[n], acc[m][n], 0, 0, 0);
                acc[m][n] = __builtin_amdgcn_mfma_f32_16x16x32_bf16(al[m], bh[n], acc[m][n], 0, 0, 0);
            }
        __syncthreads();
    }
    // C/D layout: col = lane&15, row = (lane>>4)*4 + r
#pragma unroll
    for (int m = 0; m < 4; m++) {
        int rbase = row0 + wr * 64 + m * 16 + (lane >> 4) * 4;
#pragma unroll
        for (int n = 0; n < 4; n++) {
            int c = col0 + wc * 64 + n * 16 + fr;
            if (c < Nc) {
                float bv = bias ? bias[c] : 0.f;
#pragma unroll
                for (int r = 0; r < 4; r++) {
                    int rr = rbase + r;
                    if (rr < M) C[(size_t)rr * Nc + c] = acc[m][n][r] + bv;
                }
            }
        }
    }
}

// ================= weight transpose + hi/lo split =================
struct WDesc { const float* W; ushort* Th; ushort* Tl; int K; int N; };
struct WPack { WDesc d[19]; };

__global__ void wconv_kernel(WPack p) {
    WDesc w = p.d[blockIdx.y];
    int idx = blockIdx.x * 256 + threadIdx.x;
    int total = w.K * w.N;
    if (idx >= total) return;
    int n = idx / w.K, k = idx - n * w.K;
    float v = w.W[(size_t)k * w.N + n];
    ushort hi = f2bf(v);
    w.Th[idx] = hi;
    w.Tl[idx] = f2bf(v - bf2f(hi));
}

// ================= fp32 -> hi/lo bf16 conversion =================
__global__ void conv_kernel(const float* __restrict__ in, ushort* __restrict__ oh,
                            ushort* __restrict__ ol, int total4) {
    int i = blockIdx.x * 256 + threadIdx.x;
    if (i >= total4) return;
    float4 v = *(const float4*)(in + (size_t)i * 4);
    ushort4 h, l;
    h.x = f2bf(v.x); l.x = f2bf(v.x - bf2f(h.x));
    h.y = f2bf(v.y); l.y = f2bf(v.y - bf2f(h.y));
    h.z = f2bf(v.z); l.z = f2bf(v.z - bf2f(h.z));
    h.w = f2bf(v.w); l.w = f2bf(v.w - bf2f(h.w));
    *(ushort4*)(oh + (size_t)i * 4) = h;
    *(ushort4*)(ol + (size_t)i * 4) = l;
}

// ================= CSR build =================
__global__ void hist_kernel(const int* __restrict__ dst, int* __restrict__ deg) {
    int e = blockIdx.x * blockDim.x + threadIdx.x;
    if (e >= EP) return;
    int d = (e < EE) ? dst[e] : (e - EE);
    atomicAdd(&deg[d], 1);
}

__global__ void bsum_kernel(const int* __restrict__ deg, int* __restrict__ bsum) {
    __shared__ int wsum[4];
    int i = blockIdx.x * 256 + threadIdx.x;
    int v = (i < NN) ? deg[i] : 0;
#pragma unroll
    for (int off = 32; off; off >>= 1) v += __shfl_xor(v, off);
    if ((threadIdx.x & 63) == 0) wsum[threadIdx.x >> 6] = v;
    __syncthreads();
    if (threadIdx.x == 0) bsum[blockIdx.x] = wsum[0] + wsum[1] + wsum[2] + wsum[3];
}

__global__ void bscan_kernel(const int* __restrict__ bsum, int* __restrict__ boff,
                             int* __restrict__ row_last, int nb) {
    int lane = threadIdx.x;  // 64 threads, 1 block
    int carry = 0;
    for (int base = 0; base < nb; base += 64) {
        int i = base + lane;
        int v = (i < nb) ? bsum[i] : 0;
        int x = v;
#pragma unroll
        for (int off = 1; off < 64; off <<= 1) {
            int y = __shfl_up(x, off);
            if (lane >= off) x += y;
        }
        if (i < nb) boff[i] = carry + x - v;
        carry += __shfl(x, 63);
    }
    if (lane == 0) *row_last = carry;
}

__global__ void blockscan_kernel(const int* __restrict__ deg, const int* __restrict__ boff,
                                 int* __restrict__ row_ptr, int* __restrict__ wptr) {
    __shared__ int wsum[4];
    int i = blockIdx.x * 256 + threadIdx.x;
    int v = (i < NN) ? deg[i] : 0;
    int lane = threadIdx.x & 63, w = threadIdx.x >> 6;
    int x = v;
#pragma unroll
    for (int off = 1; off < 64; off <<= 1) {
        int y = __shfl_up(x, off);
        if (lane >= off) x += y;
    }
    if (lane == 63) wsum[w] = x;
    __syncthreads();
    int wo = 0;
    for (int j = 0; j < w; j++) wo += wsum[j];
    if (i < NN) {
        int excl = boff[blockIdx.x] + wo + x - v;
        row_ptr[i] = excl;
        wptr[i] = excl;
    }
}

__global__ void scatter_kernel(const int* __restrict__ src, const int* __restrict__ dst,
                               int* __restrict__ wptr, int* __restrict__ col) {
    int e = blockIdx.x * blockDim.x + threadIdx.x;
    if (e >= EP) return;
    int s, d;
    if (e < EE) { s = src[e]; d = dst[e]; } else { s = d = e - EE; }
    int pos = atomicAdd(&wptr[d], 1);
    col[pos] = s;
}

// ================= fused GATv2 edge phase (flash-style online softmax) ====
// xl = xlr[node][0:256], xr = xlr[node][256:512]. one wave per node;
// writes hi/lo bf16 of gelu(agg + bias) for the next GEMM.
__global__ __launch_bounds__(256) void gat_fused(const float* __restrict__ xlr,
                                                 const int* __restrict__ row_ptr,
                                                 const int* __restrict__ col,
                                                 const float* __restrict__ att,
                                                 const float* __restrict__ bias,
                                                 ushort* __restrict__ outH,
                                                 ushort* __restrict__ outL) {
    int wid = (blockIdx.x * blockDim.x + threadIdx.x) >> 6;
    int lane = threadIdx.x & 63;
    if (wid >= NN) return;
    int start = row_ptr[wid], end = row_ptr[wid + 1];
    float4 xrv = *(const float4*)(xlr + (size_t)wid * XLR + 256 + lane * 4);
    float4 at  = *(const float4*)(att + lane * 4);
    float m = -1e30f, ssum = 0.f;
    float4 acc = make_float4(0.f, 0.f, 0.f, 0.f);
    for (int e = start; e < end; e++) {
        int s = col[e];
        float4 xv = *(const float4*)(xlr + (size_t)s * XLR + lane * 4);
        float p = lrelu(xv.x + xrv.x) * at.x + lrelu(xv.y + xrv.y) * at.y +
                  lrelu(xv.z + xrv.z) * at.z + lrelu(xv.w + xrv.w) * at.w;
#pragma unroll
        for (int off = 32; off; off >>= 1) p += __shfl_xor(p, off);
        if (p <= m) {                       // wave-uniform branch
            float w = __expf(p - m);
            ssum += w;
            acc.x = fmaf(w, xv.x, acc.x);
            acc.y = fmaf(w, xv.y, acc.y);
            acc.z = fmaf(w, xv.z, acc.z);
            acc.w = fmaf(w, xv.w, acc.w);
        } else {
            float sc = __expf(m - p);       // 0 on first edge
            ssum = fmaf(ssum, sc, 1.f);
            acc.x = fmaf(acc.x, sc, xv.x);
            acc.y = fmaf(acc.y, sc, xv.y);
            acc.z = fmaf(acc.z, sc, xv.z);
            acc.w = fmaf(acc.w, sc, xv.w);
            m = p;
        }
    }
    float inv = 1.f / ssum;
    float4 bv = *(const float4*)(bias + lane * 4);
    float o0 = gelu_exact(fmaf(acc.x, inv, bv.x));
    float o1 = gelu_exact(fmaf(acc.y, inv, bv.y));
    float o2 = gelu_exact(fmaf(acc.z, inv, bv.z));
    float o3 = gelu_exact(fmaf(acc.w, inv, bv.w));
    ushort4 h, l;
    h.x = f2bf(o0); l.x = f2bf(o0 - bf2f(h.x));
    h.y = f2bf(o1); l.y = f2bf(o1 - bf2f(h.y));
    h.z = f2bf(o2); l.z = f2bf(o2 - bf2f(h.z));
    h.w = f2bf(o3); l.w = f2bf(o3 - bf2f(h.w));
    size_t o = (size_t)wid * HH + lane * 4;
    *(ushort4*)(outH + o) = h;
    *(ushort4*)(outL + o) = l;
}

// ================= mu/logstd/z + bf16 split of z =================
// muls[MP][128]: cols 0..63 = h@mu_W, 64..127 = h@ls_W (no bias yet)
__global__ void z_kernel(const float* __restrict__ muls,
                         const float* __restrict__ mu_b, const float* __restrict__ ls_b,
                         const float* __restrict__ eps,
                         float* __restrict__ mu, float* __restrict__ lstd,
                         float* __restrict__ z,
                         ushort* __restrict__ zh, ushort* __restrict__ zl) {
    int i = blockIdx.x * 256 + threadIdx.x;
    if (i >= NN * LL) return;
    int row = i >> 6, j = i & 63;
    float mv = muls[(size_t)row * 128 + j] + mu_b[j];
    float lv = fminf(muls[(size_t)row * 128 + 64 + j] + ls_b[j], 10.f);
    float zv = fmaf(eps[i], __expf(lv), mv);
    mu[i] = mv;
    lstd[i] = lv;
    z[i] = zv;
    ushort h = f2bf(zv);
    zh[i] = h;
    zl[i] = f2bf(zv - bf2f(h));
}

extern "C" void kernel_launch(void* const* d_in, const int* in_sizes, int n_in,
                              void* d_out, int out_size, void* d_ws, size_t ws_size,
                              hipStream_t stream) {
    const float* x       = (const float*)d_in[0];
    const int*   ei      = (const int*)d_in[1];
    const float* eps     = (const float*)d_in[2];
    const float* enc_Wl  = (const float*)d_in[3];
    const float* enc_Wr  = (const float*)d_in[4];
    const float* enc_att = (const float*)d_in[5];
    const float* enc_b   = (const float*)d_in[6];
    const float* mu_W    = (const float*)d_in[7];
    const float* mu_b    = (const float*)d_in[8];
    const float* ls_W    = (const float*)d_in[9];
    const float* ls_b    = (const float*)d_in[10];
    const float* dec0_Wl = (const float*)d_in[11];
    const float* dec0_Wr = (const float*)d_in[12];
    const float* dec0_att= (const float*)d_in[13];
    const float* dec0_b  = (const float*)d_in[14];
    const float* dec_Wl  = (const float*)d_in[15];
    const float* dec_Wr  = (const float*)d_in[16];
    const float* dec_att = (const float*)d_in[17];
    const float* dec_b   = (const float*)d_in[18];
    const float* out_W   = (const float*)d_in[19];
    const float* out_b   = (const float*)d_in[20];

    const int* esrc = ei;
    const int* edst = ei + EE;

    float* out_f = (float*)d_out;
    float* xrec = out_f;
    float* z    = out_f + (size_t)NN * DD;
    float* mu   = z + (size_t)NN * LL;
    float* lstd = mu + (size_t)NN * LL;

    // ---- workspace layout ----
    float* wsf = (float*)d_ws;
    float* xlr = wsf;                               // MP*512 f32 (also muls MP*128)
    ushort* Ah = (ushort*)(xlr + (size_t)MP * XLR); // MP*256 bf16
    ushort* Al = Ah + (size_t)MP * 256;
    ushort* Th = Al + (size_t)MP * 256;             // 1,048,576 bf16
    ushort* Tl = Th + 1048576;
    int* deg     = (int*)(Tl + 1048576);
    int* row_ptr = deg + NN;
    int* wptr    = row_ptr + NN + 1;
    int* col     = wptr + NN;
    int* bsum    = col + EP;
    int* boff    = bsum + 256;

    // weight pack: per-layer Wl/Wr pairs CONTIGUOUS so fused Nc=512 GEMM works
    WPack p;
    size_t off = 0;
    int wi = 0;
    auto add = [&](const float* W, int K, int N) {
        p.d[wi] = {W, Th + off, Tl + off, K, N};
        off += (size_t)K * N;
        wi++;
    };
    for (int l = 0; l < 4; l++) {                     // 0..7: enc (Wl,Wr)*4
        add(enc_Wl + (size_t)l * DD * HH, DD, HH);
        add(enc_Wr + (size_t)l * DD * HH, DD, HH);
    }
    add(dec0_Wl, LL, HH);                             // 8,9
    add(dec0_Wr, LL, HH);
    for (int l = 0; l < 3; l++) {                     // 10..15: dec (Wl,Wr)*3
        add(dec_Wl + (size_t)l * HH * HH, HH, HH);
        add(dec_Wr + (size_t)l * HH * HH, HH, HH);
    }
    add(out_W, HH, DD);                               // 16
    add(mu_W, HH, LL);                                // 17,18 contiguous -> Nc=128
    add(ls_W, HH, LL);

    const int eb = (EP + 255) / 256;
    const int nb = (NN * 64 + 255) / 256;
    const int cb = (NN * 64 + 255) / 256;   // conv blocks (total4 = NN*64)
    dim3 mmg_pair(4, MP / 128);             // Nc=512 fused Wl|Wr
    dim3 mmg_out(2, MP / 128);              // Nc=256
    dim3 mmg_muls(1, MP / 128);             // Nc=128 fused mu|ls

    // ---- weight conversion + CSR build ----
    wconv_kernel<<<dim3(256, 19), 256, 0, stream>>>(p);
    hipMemsetAsync(deg, 0, (size_t)NN * sizeof(int), stream);
    hist_kernel<<<eb, 256, 0, stream>>>(edst, deg);
    bsum_kernel<<<NB2, 256, 0, stream>>>(deg, bsum);
    bscan_kernel<<<1, 64, 0, stream>>>(bsum, boff, row_ptr + NN, NB2);
    blockscan_kernel<<<NB2, 256, 0, stream>>>(deg, boff, row_ptr, wptr);
    scatter_kernel<<<eb, 256, 0, stream>>>(esrc, edst, wptr, col);

    // ---- x -> hi/lo ----
    conv_kernel<<<cb, 256, 0, stream>>>(x, Ah, Al, NN * 64);

    // ---- encoder ----
    for (int l = 0; l < 4; l++) {
        mm_bf16<<<mmg_pair, 256, 0, stream>>>(Ah, Al, p.d[2 * l].Th, p.d[2 * l].Tl,
                                              nullptr, xlr, NN, DD, XLR);
        gat_fused<<<nb, 256, 0, stream>>>(xlr, row_ptr, col,
                                          enc_att + (size_t)l * HH,
                                          enc_b + (size_t)l * HH, Ah, Al);
    }

    // ---- mu / logstd / z (fused Nc=128 GEMM into xlr-as-muls) ----
    mm_bf16<<<mmg_muls, 256, 0, stream>>>(Ah, Al, p.d[17].Th, p.d[17].Tl, nullptr,
                                          xlr, NN, HH, 128);
    z_kernel<<<(NN * LL + 255) / 256, 256, 0, stream>>>(xlr, mu_b, ls_b, eps,
                                                        mu, lstd, z, Ah, Al);

    // ---- decoder ----
    for (int l = 0; l < 4; l++) {
        const ushort *BH, *BL;
        const float *at, *bb;
        int K;
        if (l == 0) {
            BH = p.d[8].Th; BL = p.d[8].Tl;      // dec0 Wl|Wr combined [512][64]
            at = dec0_att; bb = dec0_b; K = LL;
        } else {
            BH = p.d[10 + 2 * (l - 1)].Th; BL = p.d[10 + 2 * (l - 1)].Tl;
            at = dec_att + (size_t)(l - 1) * HH;
            bb = dec_b + (size_t)(l - 1) * HH;
            K = HH;
        }
        mm_bf16<<<mmg_pair, 256, 0, stream>>>(Ah, Al, BH, BL, nullptr, xlr, NN, K, XLR);
        gat_fused<<<nb, 256, 0, stream>>>(xlr, row_ptr, col, at, bb, Ah, Al);
    }

    // ---- output projection ----
    mm_bf16<<<mmg_out, 256, 0, stream>>>(Ah, Al, p.d[16].Th, p.d[16].Tl, out_b,
                                         xrec, NN, HH, DD);
}

// Round 6
// 1534.996 us; speedup vs baseline: 2.8046x; 1.2545x over previous
//
#include <hip/hip_runtime.h>
#include <hip/hip_fp16.h>
#include <math.h>

#define NN 50000
#define EE 800000
#define DD 256
#define HH 256
#define LL 64
#define EP (EE + NN)          // edges + self loops
#define MP 50048              // 391 * 128, padded row count
#define NB2 ((NN + 255) / 256)
#define XLR 512               // fused xl|xr row stride (f16)

typedef __attribute__((ext_vector_type(8))) short short8;
typedef __attribute__((ext_vector_type(4))) float f32x4;

__device__ __forceinline__ float gelu_exact(float x) {
    return 0.5f * x * (1.f + erff(x * 0.70710678118654752f));
}
__device__ __forceinline__ ushort f2bf(float x) {
    union { float f; unsigned u; } v; v.f = x;
    unsigned r = v.u + 0x7fff + ((v.u >> 16) & 1);
    return (ushort)(r >> 16);
}
__device__ __forceinline__ float bf2f(ushort h) {
    union { float f; unsigned u; } v; v.u = ((unsigned)h) << 16;
    return v.f;
}

// ================= split-bf16 MFMA GEMM =================
// C[M,Nc] = A[M,K] @ B^T + bias, A as hi/lo bf16 [MP][K], B as [Nc][K] hi/lo.
// Tile 128x128, BK=32, 4 waves (2x2), per wave 4x4 frags of 16x16x32.
// OM=0: C float; OM=1: C __half (xlr buffer for the GAT gather).
template <int OM>
__global__ __launch_bounds__(256) void mm_bf16(const ushort* __restrict__ Ah,
                                               const ushort* __restrict__ Al,
                                               const ushort* __restrict__ Bh,
                                               const ushort* __restrict__ Bl,
                                               const float* __restrict__ bias,
                                               void* __restrict__ Cout,
                                               int M, int K, int Nc) {
    __shared__ ushort As_h[128][40];
    __shared__ ushort As_l[128][40];
    __shared__ ushort Bs_h[128][40];
    __shared__ ushort Bs_l[128][40];
    const int tid = threadIdx.x;
    const int lane = tid & 63;
    const int wid = tid >> 6;
    const int wr = wid >> 1, wc = wid & 1;
    const int row0 = blockIdx.y * 128;
    const int col0 = blockIdx.x * 128;
    const int srow = tid >> 2;       // 0..63
    const int sk = (tid & 3) << 3;   // 0,8,16,24
    const int fr = lane & 15;
    const int kg = (lane >> 4) << 3; // 0,8,16,24

    f32x4 acc[4][4] = {};

    for (int k0 = 0; k0 < K; k0 += 32) {
#pragma unroll
        for (int h = 0; h < 2; h++) {
            int r = srow + h * 64;
            size_t ga = (size_t)(row0 + r) * K + k0 + sk;
            *(int4*)(&As_h[r][sk]) = *(const int4*)(Ah + ga);
            *(int4*)(&As_l[r][sk]) = *(const int4*)(Al + ga);
            int c = col0 + r;
            int4 bh4 = {0, 0, 0, 0}, bl4 = {0, 0, 0, 0};
            if (c < Nc) {
                size_t gb = (size_t)c * K + k0 + sk;
                bh4 = *(const int4*)(Bh + gb);
                bl4 = *(const int4*)(Bl + gb);
            }
            *(int4*)(&Bs_h[r][sk]) = bh4;
            *(int4*)(&Bs_l[r][sk]) = bl4;
        }
        __syncthreads();
        short8 ah[4], al[4], bh[4], bl[4];
#pragma unroll
        for (int m = 0; m < 4; m++) {
            ah[m] = *(const short8*)&As_h[wr * 64 + m * 16 + fr][kg];
            al[m] = *(const short8*)&As_l[wr * 64 + m * 16 + fr][kg];
        }
#pragma unroll
        for (int n = 0; n < 4; n++) {
            bh[n] = *(const short8*)&Bs_h[wc * 64 + n * 16 + fr][kg];
            bl[n] = *(const short8*)&Bs_l[wc * 64 + n * 16 + fr][kg];
        }
#pragma unroll
        for (int m = 0; m < 4; m++)
#pragma unroll
            for (int n = 0; n < 4; n++) {
                acc[m][n] = __builtin_amdgcn_mfma_f32_16x16x32_bf16(ah[m], bh[n], acc[m][n], 0, 0, 0);
                acc[m][n] = __builtin_amdgcn_mfma_f32_16x16x32_bf16(ah[m], bl[n], acc[m][n], 0, 0, 0);
                acc[m][n] = __builtin_amdgcn_mfma_f32_16x16x32_bf16(al[m], bh[n], acc[m][n], 0, 0, 0);
            }
        __syncthreads();
    }
    // C/D layout: col = lane&15, row = (lane>>4)*4 + r
#pragma unroll
    for (int m = 0; m < 4; m++) {
        int rbase = row0 + wr * 64 + m * 16 + (lane >> 4) * 4;
#pragma unroll
        for (int n = 0; n < 4; n++) {
            int c = col0 + wc * 64 + n * 16 + fr;
            if (c < Nc) {
                float bv = bias ? bias[c] : 0.f;
#pragma unroll
                for (int r = 0; r < 4; r++) {
                    int rr = rbase + r;
                    if (rr < M) {
                        float v = acc[m][n][r] + bv;
                        if (OM == 0)
                            ((float*)Cout)[(size_t)rr * Nc + c] = v;
                        else
                            ((__half*)Cout)[(size_t)rr * Nc + c] = __float2half_rn(v);
                    }
                }
            }
        }
    }
}

// ================= weight transpose + hi/lo split =================
struct WDesc { const float* W; ushort* Th; ushort* Tl; int K; int N; };
struct WPack { WDesc d[19]; };

__global__ void wconv_kernel(WPack p) {
    WDesc w = p.d[blockIdx.y];
    int idx = blockIdx.x * 256 + threadIdx.x;
    int total = w.K * w.N;
    if (idx >= total) return;
    int n = idx / w.K, k = idx - n * w.K;
    float v = w.W[(size_t)k * w.N + n];
    ushort hi = f2bf(v);
    w.Th[idx] = hi;
    w.Tl[idx] = f2bf(v - bf2f(hi));
}

// ================= fp32 -> hi/lo bf16 conversion =================
__global__ void conv_kernel(const float* __restrict__ in, ushort* __restrict__ oh,
                            ushort* __restrict__ ol, int total4) {
    int i = blockIdx.x * 256 + threadIdx.x;
    if (i >= total4) return;
    float4 v = *(const float4*)(in + (size_t)i * 4);
    ushort4 h, l;
    h.x = f2bf(v.x); l.x = f2bf(v.x - bf2f(h.x));
    h.y = f2bf(v.y); l.y = f2bf(v.y - bf2f(h.y));
    h.z = f2bf(v.z); l.z = f2bf(v.z - bf2f(h.z));
    h.w = f2bf(v.w); l.w = f2bf(v.w - bf2f(h.w));
    *(ushort4*)(oh + (size_t)i * 4) = h;
    *(ushort4*)(ol + (size_t)i * 4) = l;
}

// ================= CSR build =================
__global__ void hist_kernel(const int* __restrict__ dst, int* __restrict__ deg) {
    int e = blockIdx.x * blockDim.x + threadIdx.x;
    if (e >= EP) return;
    int d = (e < EE) ? dst[e] : (e - EE);
    atomicAdd(&deg[d], 1);
}

__global__ void bsum_kernel(const int* __restrict__ deg, int* __restrict__ bsum) {
    __shared__ int wsum[4];
    int i = blockIdx.x * 256 + threadIdx.x;
    int v = (i < NN) ? deg[i] : 0;
#pragma unroll
    for (int off = 32; off; off >>= 1) v += __shfl_xor(v, off);
    if ((threadIdx.x & 63) == 0) wsum[threadIdx.x >> 6] = v;
    __syncthreads();
    if (threadIdx.x == 0) bsum[blockIdx.x] = wsum[0] + wsum[1] + wsum[2] + wsum[3];
}

__global__ void bscan_kernel(const int* __restrict__ bsum, int* __restrict__ boff,
                             int* __restrict__ row_last, int nb) {
    int lane = threadIdx.x;  // 64 threads, 1 block
    int carry = 0;
    for (int base = 0; base < nb; base += 64) {
        int i = base + lane;
        int v = (i < nb) ? bsum[i] : 0;
        int x = v;
#pragma unroll
        for (int off = 1; off < 64; off <<= 1) {
            int y = __shfl_up(x, off);
            if (lane >= off) x += y;
        }
        if (i < nb) boff[i] = carry + x - v;
        carry += __shfl(x, 63);
    }
    if (lane == 0) *row_last = carry;
}

__global__ void blockscan_kernel(const int* __restrict__ deg, const int* __restrict__ boff,
                                 int* __restrict__ row_ptr, int* __restrict__ wptr) {
    __shared__ int wsum[4];
    int i = blockIdx.x * 256 + threadIdx.x;
    int v = (i < NN) ? deg[i] : 0;
    int lane = threadIdx.x & 63, w = threadIdx.x >> 6;
    int x = v;
#pragma unroll
    for (int off = 1; off < 64; off <<= 1) {
        int y = __shfl_up(x, off);
        if (lane >= off) x += y;
    }
    if (lane == 63) wsum[w] = x;
    __syncthreads();
    int wo = 0;
    for (int j = 0; j < w; j++) wo += wsum[j];
    if (i < NN) {
        int excl = boff[blockIdx.x] + wo + x - v;
        row_ptr[i] = excl;
        wptr[i] = excl;
    }
}

__global__ void scatter_kernel(const int* __restrict__ src, const int* __restrict__ dst,
                               int* __restrict__ wptr, int* __restrict__ col) {
    int e = blockIdx.x * blockDim.x + threadIdx.x;
    if (e >= EP) return;
    int s, d;
    if (e < EE) { s = src[e]; d = dst[e]; } else { s = d = e - EE; }
    int pos = atomicAdd(&wptr[d], 1);
    col[pos] = s;
}

// ================= fused GATv2 edge phase =================
// xlr is f16: row = node, cols 0..255 = xl, 256..511 = xr.
// One wave per node, split as 4 groups of 16 lanes; each group processes one
// edge per iteration (16 elems/lane, packed-f16 score math, f32 acc/softmax).
// lrelu(x) = 0.6x + 0.4|x| (exact for slope 0.2); packed |x| = and 0x7fff7fff.
__global__ __launch_bounds__(256) void gat_fused(const __half* __restrict__ xlr,
                                                 const int* __restrict__ row_ptr,
                                                 const int* __restrict__ col,
                                                 const float* __restrict__ att,
                                                 const float* __restrict__ bias,
                                                 ushort* __restrict__ outH,
                                                 ushort* __restrict__ outL) {
    int wid = blockIdx.x * 4 + (threadIdx.x >> 6);
    if (wid >= NN) return;
    const int lane = threadIdx.x & 63;
    const int g = lane >> 4, sl = lane & 15;
    const int start = row_ptr[wid], end = row_ptr[wid + 1];

    union U8 { uint4 q[2]; __half2 h[8]; unsigned u[8]; };

    // xr slice (this node), elems sl*16 .. sl*16+15
    U8 xr;
    {
        const uint4* xrp = (const uint4*)(xlr + (size_t)wid * XLR + 256 + sl * 16);
        xr.q[0] = xrp[0]; xr.q[1] = xrp[1];
    }
    // att slice as packed f16
    U8 at;
    {
        const float4* ap = (const float4*)(att + sl * 16);
        float4 a0 = ap[0], a1 = ap[1], a2 = ap[2], a3 = ap[3];
        at.h[0] = __floats2half2_rn(a0.x, a0.y); at.h[1] = __floats2half2_rn(a0.z, a0.w);
        at.h[2] = __floats2half2_rn(a1.x, a1.y); at.h[3] = __floats2half2_rn(a1.z, a1.w);
        at.h[4] = __floats2half2_rn(a2.x, a2.y); at.h[5] = __floats2half2_rn(a2.z, a2.w);
        at.h[6] = __floats2half2_rn(a3.x, a3.y); at.h[7] = __floats2half2_rn(a3.z, a3.w);
    }
    const __half2 c06 = __floats2half2_rn(0.6f, 0.6f);
    const __half2 c04 = __floats2half2_rn(0.4f, 0.4f);

    float m = -1e30f, ssum = 0.f;
    float acc[16];
#pragma unroll
    for (int j = 0; j < 16; j++) acc[j] = 0.f;

    for (int e0 = start; e0 < end; e0 += 4) {
        int eg = e0 + g;
        bool valid = eg < end;
        int s = col[valid ? eg : (end - 1)];
        U8 xv;
        {
            const uint4* xp = (const uint4*)(xlr + (size_t)s * XLR + sl * 16);
            xv.q[0] = xp[0]; xv.q[1] = xp[1];
        }
        // score: dot(att, lrelu(xl[src] + xr[dst])) in packed f16
        __half2 p2 = __floats2half2_rn(0.f, 0.f);
#pragma unroll
        for (int i = 0; i < 8; i++) {
            __half2 s2 = __hadd2(xv.h[i], xr.h[i]);
            union { __half2 h; unsigned u; } ab; ab.h = s2; ab.u &= 0x7fff7fffu;
            __half2 l2 = __hfma2(s2, c06, __hmul2(ab.h, c04));  // lrelu
            p2 = __hfma2(l2, at.h[i], p2);
        }
        float pf = __low2float(p2) + __high2float(p2);
#pragma unroll
        for (int off = 1; off < 16; off <<= 1) pf += __shfl_xor(pf, off);

        if (valid) {
            if (pf <= m) {
                float w = __expf(pf - m);
                ssum += w;
#pragma unroll
                for (int j = 0; j < 8; j++) {
                    float2 f = __half22float2(xv.h[j]);
                    acc[2 * j]     = fmaf(w, f.x, acc[2 * j]);
                    acc[2 * j + 1] = fmaf(w, f.y, acc[2 * j + 1]);
                }
            } else {
                float sc = __expf(m - pf);   // 0 on first edge
                ssum = fmaf(ssum, sc, 1.f);
#pragma unroll
                for (int j = 0; j < 8; j++) {
                    float2 f = __half22float2(xv.h[j]);
                    acc[2 * j]     = fmaf(acc[2 * j], sc, f.x);
                    acc[2 * j + 1] = fmaf(acc[2 * j + 1], sc, f.y);
                }
                m = pf;
            }
        }
    }

    // merge the 4 groups' (m, ssum, acc) — butterfly over lane bits 16, 32
#pragma unroll
    for (int off = 16; off <= 32; off <<= 1) {
        float m2 = __shfl_xor(m, off);
        float s2 = __shfl_xor(ssum, off);
        float mn = fmaxf(m, m2);
        float f1 = __expf(m - mn);
        float f2 = __expf(m2 - mn);
        ssum = ssum * f1 + s2 * f2;
#pragma unroll
        for (int j = 0; j < 16; j++)
            acc[j] = acc[j] * f1 + __shfl_xor(acc[j], off) * f2;
        m = mn;
    }

    if (g == 0) {
        float inv = 1.f / ssum;
        const float4* bp = (const float4*)(bias + sl * 16);
        float4 b4[4] = {bp[0], bp[1], bp[2], bp[3]};
        const float* bf = (const float*)b4;
        union { ushort u[16]; uint4 q[2]; } Hh, Ll;
#pragma unroll
        for (int j = 0; j < 16; j++) {
            float o = gelu_exact(fmaf(acc[j], inv, bf[j]));
            ushort h = f2bf(o);
            Hh.u[j] = h;
            Ll.u[j] = f2bf(o - bf2f(h));
        }
        size_t ob = (size_t)wid * HH + sl * 16;
        *(uint4*)(outH + ob) = Hh.q[0];
        *(uint4*)(outH + ob + 8) = Hh.q[1];
        *(uint4*)(outL + ob) = Ll.q[0];
        *(uint4*)(outL + ob + 8) = Ll.q[1];
    }
}

// ================= mu/logstd/z + bf16 split of z =================
// muls[MP][128]: cols 0..63 = h@mu_W, 64..127 = h@ls_W (no bias yet)
__global__ void z_kernel(const float* __restrict__ muls,
                         const float* __restrict__ mu_b, const float* __restrict__ ls_b,
                         const float* __restrict__ eps,
                         float* __restrict__ mu, float* __restrict__ lstd,
                         float* __restrict__ z,
                         ushort* __restrict__ zh, ushort* __restrict__ zl) {
    int i = blockIdx.x * 256 + threadIdx.x;
    if (i >= NN * LL) return;
    int row = i >> 6, j = i & 63;
    float mv = muls[(size_t)row * 128 + j] + mu_b[j];
    float lv = fminf(muls[(size_t)row * 128 + 64 + j] + ls_b[j], 10.f);
    float zv = fmaf(eps[i], __expf(lv), mv);
    mu[i] = mv;
    lstd[i] = lv;
    z[i] = zv;
    ushort h = f2bf(zv);
    zh[i] = h;
    zl[i] = f2bf(zv - bf2f(h));
}

extern "C" void kernel_launch(void* const* d_in, const int* in_sizes, int n_in,
                              void* d_out, int out_size, void* d_ws, size_t ws_size,
                              hipStream_t stream) {
    const float* x       = (const float*)d_in[0];
    const int*   ei      = (const int*)d_in[1];
    const float* eps     = (const float*)d_in[2];
    const float* enc_Wl  = (const float*)d_in[3];
    const float* enc_Wr  = (const float*)d_in[4];
    const float* enc_att = (const float*)d_in[5];
    const float* enc_b   = (const float*)d_in[6];
    const float* mu_W    = (const float*)d_in[7];
    const float* mu_b    = (const float*)d_in[8];
    const float* ls_W    = (const float*)d_in[9];
    const float* ls_b    = (const float*)d_in[10];
    const float* dec0_Wl = (const float*)d_in[11];
    const float* dec0_Wr = (const float*)d_in[12];
    const float* dec0_att= (const float*)d_in[13];
    const float* dec0_b  = (const float*)d_in[14];
    const float* dec_Wl  = (const float*)d_in[15];
    const float* dec_Wr  = (const float*)d_in[16];
    const float* dec_att = (const float*)d_in[17];
    const float* dec_b   = (const float*)d_in[18];
    const float* out_W   = (const float*)d_in[19];
    const float* out_b   = (const float*)d_in[20];

    const int* esrc = ei;
    const int* edst = ei + EE;

    float* out_f = (float*)d_out;
    float* xrec = out_f;
    float* z    = out_f + (size_t)NN * DD;
    float* mu   = z + (size_t)NN * LL;
    float* lstd = mu + (size_t)NN * LL;

    // ---- workspace layout ----
    float* wsf = (float*)d_ws;
    __half* xlr = (__half*)wsf;                     // MP*512 f16  (= MP*256 floats)
    float* muls = wsf + (size_t)MP * 256;           // MP*128 f32
    ushort* Ah = (ushort*)(muls + (size_t)MP * 128);// MP*256 bf16
    ushort* Al = Ah + (size_t)MP * 256;
    ushort* Th = Al + (size_t)MP * 256;             // 1,048,576 bf16
    ushort* Tl = Th + 1048576;
    int* deg     = (int*)(Tl + 1048576);
    int* row_ptr = deg + NN;
    int* wptr    = row_ptr + NN + 1;
    int* col     = wptr + NN;
    int* bsum    = col + EP;
    int* boff    = bsum + 256;

    // weight pack: per-layer Wl/Wr pairs CONTIGUOUS so fused Nc=512 GEMM works
    WPack p;
    size_t off = 0;
    int wi = 0;
    auto add = [&](const float* W, int K, int N) {
        p.d[wi] = {W, Th + off, Tl + off, K, N};
        off += (size_t)K * N;
        wi++;
    };
    for (int l = 0; l < 4; l++) {                     // 0..7: enc (Wl,Wr)*4
        add(enc_Wl + (size_t)l * DD * HH, DD, HH);
        add(enc_Wr + (size_t)l * DD * HH, DD, HH);
    }
    add(dec0_Wl, LL, HH);                             // 8,9
    add(dec0_Wr, LL, HH);
    for (int l = 0; l < 3; l++) {                     // 10..15: dec (Wl,Wr)*3
        add(dec_Wl + (size_t)l * HH * HH, HH, HH);
        add(dec_Wr + (size_t)l * HH * HH, HH, HH);
    }
    add(out_W, HH, DD);                               // 16
    add(mu_W, HH, LL);                                // 17,18 contiguous -> Nc=128
    add(ls_W, HH, LL);

    const int eb = (EP + 255) / 256;
    const int nb = (NN + 3) / 4;            // gat: 4 nodes (waves) per block
    const int cb = (NN * 64 + 255) / 256;
    dim3 mmg_pair(4, MP / 128);             // Nc=512 fused Wl|Wr
    dim3 mmg_out(2, MP / 128);              // Nc=256
    dim3 mmg_muls(1, MP / 128);             // Nc=128 fused mu|ls

    // ---- weight conversion + CSR build ----
    wconv_kernel<<<dim3(256, 19), 256, 0, stream>>>(p);
    (void)hipMemsetAsync(deg, 0, (size_t)NN * sizeof(int), stream);
    hist_kernel<<<eb, 256, 0, stream>>>(edst, deg);
    bsum_kernel<<<NB2, 256, 0, stream>>>(deg, bsum);
    bscan_kernel<<<1, 64, 0, stream>>>(bsum, boff, row_ptr + NN, NB2);
    blockscan_kernel<<<NB2, 256, 0, stream>>>(deg, boff, row_ptr, wptr);
    scatter_kernel<<<eb, 256, 0, stream>>>(esrc, edst, wptr, col);

    // ---- x -> hi/lo ----
    conv_kernel<<<cb, 256, 0, stream>>>(x, Ah, Al, NN * 64);

    // ---- encoder ----
    for (int l = 0; l < 4; l++) {
        mm_bf16<1><<<mmg_pair, 256, 0, stream>>>(Ah, Al, p.d[2 * l].Th, p.d[2 * l].Tl,
                                                 nullptr, xlr, NN, DD, XLR);
        gat_fused<<<nb, 256, 0, stream>>>(xlr, row_ptr, col,
                                          enc_att + (size_t)l * HH,
                                          enc_b + (size_t)l * HH, Ah, Al);
    }

    // ---- mu / logstd / z (fused Nc=128 GEMM) ----
    mm_bf16<0><<<mmg_muls, 256, 0, stream>>>(Ah, Al, p.d[17].Th, p.d[17].Tl, nullptr,
                                             muls, NN, HH, 128);
    z_kernel<<<(NN * LL + 255) / 256, 256, 0, stream>>>(muls, mu_b, ls_b, eps,
                                                        mu, lstd, z, Ah, Al);

    // ---- decoder ----
    for (int l = 0; l < 4; l++) {
        const ushort *BH, *BL;
        const float *at, *bb;
        int K;
        if (l == 0) {
            BH = p.d[8].Th; BL = p.d[8].Tl;      // dec0 Wl|Wr combined [512][64]
            at = dec0_att; bb = dec0_b; K = LL;
        } else {
            BH = p.d[10 + 2 * (l - 1)].Th; BL = p.d[10 + 2 * (l - 1)].Tl;
            at = dec_att + (size_t)(l - 1) * HH;
            bb = dec_b + (size_t)(l - 1) * HH;
            K = HH;
        }
        mm_bf16<1><<<mmg_pair, 256, 0, stream>>>(Ah, Al, BH, BL, nullptr, xlr, NN, K, XLR);
        gat_fused<<<nb, 256, 0, stream>>>(xlr, row_ptr, col, at, bb, Ah, Al);
    }

    // ---- output projection ----
    mm_bf16<0><<<mmg_out, 256, 0, stream>>>(Ah, Al, p.d[16].Th, p.d[16].Tl, out_b,
                                            xrec, NN, HH, DD);
}

// Round 7
// 1498.488 us; speedup vs baseline: 2.8729x; 1.0244x over previous
//
#include <hip/hip_runtime.h>
#include <hip/hip_fp16.h>
#include <math.h>

#define NN 50000
#define EE 800000
#define DD 256
#define HH 256
#define LL 64
#define EP (EE + NN)          // edges + self loops
#define MP 50048              // 391 * 128, padded row count
#define NB2 ((NN + 255) / 256)
#define XLR 512               // fused xl|xr row stride (f16)

typedef __attribute__((ext_vector_type(8))) short short8;
typedef __attribute__((ext_vector_type(4))) float f32x4;

__device__ __forceinline__ float gelu_exact(float x) {
    return 0.5f * x * (1.f + erff(x * 0.70710678118654752f));
}
__device__ __forceinline__ ushort f2bf(float x) {
    union { float f; unsigned u; } v; v.f = x;
    unsigned r = v.u + 0x7fff + ((v.u >> 16) & 1);
    return (ushort)(r >> 16);
}
__device__ __forceinline__ float bf2f(ushort h) {
    union { float f; unsigned u; } v; v.u = ((unsigned)h) << 16;
    return v.f;
}

// async global -> LDS, 16B per lane, wave-uniform LDS base + lane*16
__device__ __forceinline__ void gload_lds16(const ushort* g, ushort* l) {
    __builtin_amdgcn_global_load_lds(
        (__attribute__((address_space(1))) unsigned int*)(g),
        (__attribute__((address_space(3))) unsigned int*)(l), 16, 0, 0);
}

// ================= split-bf16 MFMA GEMM (global_load_lds staging) =========
// C[M,Nc] = A[M,K] @ B^T + bias, A hi/lo bf16 [MP][K], B [Nc][K] hi/lo.
// Tile 128x128, BK=32, 4 waves (2x2), per wave 4x4 frags of 16x16x32.
// Staging: wave w fills one linear 8KB LDS buffer (Ah/Al/Bh/Bl) via 8
// global_load_lds chunks (1KB each: 16 rows x 64B).
// OM=0: C float; OM=1: C __half (xlr buffer for the GAT gather).
template <int OM>
__global__ __launch_bounds__(256) void mm_bf16(const ushort* __restrict__ Ah,
                                               const ushort* __restrict__ Al,
                                               const ushort* __restrict__ Bh,
                                               const ushort* __restrict__ Bl,
                                               const float* __restrict__ bias,
                                               void* __restrict__ Cout,
                                               int M, int K, int Nc) {
    __shared__ ushort As_h[128 * 32];
    __shared__ ushort As_l[128 * 32];
    __shared__ ushort Bs_h[128 * 32];
    __shared__ ushort Bs_l[128 * 32];
    const int tid = threadIdx.x;
    const int lane = tid & 63;
    const int wid = tid >> 6;
    const int wr = wid >> 1, wc = wid & 1;
    const int row0 = blockIdx.y * 128;
    const int col0 = blockIdx.x * 128;
    const int fr = lane & 15;
    const int kg = (lane >> 4) << 3; // 0,8,16,24

    // staging assignment: wave -> buffer
    const ushort* gsrc = (wid == 0) ? Ah : (wid == 1) ? Al : (wid == 2) ? Bh : Bl;
    ushort* ldst = (wid == 0) ? As_h : (wid == 1) ? As_l : (wid == 2) ? Bs_h : Bs_l;
    const int rbase = (wid < 2) ? row0 : col0;
    const int crow = lane >> 2;        // 0..15
    const int ccol = (lane & 3) << 3;  // ushort col 0,8,16,24

    f32x4 acc[4][4] = {};

    for (int k0 = 0; k0 < K; k0 += 32) {
#pragma unroll
        for (int i = 0; i < 8; i++) {
            const ushort* src = gsrc + (size_t)(rbase + i * 16 + crow) * K + k0 + ccol;
            gload_lds16(src, ldst + i * 512);
        }
        __syncthreads();
        short8 ah[4], al[4], bh[4], bl[4];
#pragma unroll
        for (int m = 0; m < 4; m++) {
            int r = (wr * 64 + m * 16 + fr) * 32 + kg;
            ah[m] = *(const short8*)&As_h[r];
            al[m] = *(const short8*)&As_l[r];
        }
#pragma unroll
        for (int n = 0; n < 4; n++) {
            int r = (wc * 64 + n * 16 + fr) * 32 + kg;
            bh[n] = *(const short8*)&Bs_h[r];
            bl[n] = *(const short8*)&Bs_l[r];
        }
#pragma unroll
        for (int m = 0; m < 4; m++)
#pragma unroll
            for (int n = 0; n < 4; n++) {
                acc[m][n] = __builtin_amdgcn_mfma_f32_16x16x32_bf16(ah[m], bh[n], acc[m][n], 0, 0, 0);
                acc[m][n] = __builtin_amdgcn_mfma_f32_16x16x32_bf16(ah[m], bl[n], acc[m][n], 0, 0, 0);
                acc[m][n] = __builtin_amdgcn_mfma_f32_16x16x32_bf16(al[m], bh[n], acc[m][n], 0, 0, 0);
            }
        __syncthreads();
    }
    // C/D layout: col = lane&15, row = (lane>>4)*4 + r
#pragma unroll
    for (int m = 0; m < 4; m++) {
        int rbase2 = row0 + wr * 64 + m * 16 + (lane >> 4) * 4;
#pragma unroll
        for (int n = 0; n < 4; n++) {
            int c = col0 + wc * 64 + n * 16 + fr;
            float bv = bias ? bias[c] : 0.f;
#pragma unroll
            for (int r = 0; r < 4; r++) {
                int rr = rbase2 + r;
                if (rr < M) {
                    float v = acc[m][n][r] + bv;
                    if (OM == 0)
                        ((float*)Cout)[(size_t)rr * Nc + c] = v;
                    else
                        ((__half*)Cout)[(size_t)rr * Nc + c] = __float2half_rn(v);
                }
            }
        }
    }
}

// ================= weight transpose + hi/lo split =================
struct WDesc { const float* W; ushort* Th; ushort* Tl; int K; int N; };
struct WPack { WDesc d[19]; };

__global__ void wconv_kernel(WPack p) {
    WDesc w = p.d[blockIdx.y];
    int idx = blockIdx.x * 256 + threadIdx.x;
    int total = w.K * w.N;
    if (idx >= total) return;
    int n = idx / w.K, k = idx - n * w.K;
    float v = w.W[(size_t)k * w.N + n];
    ushort hi = f2bf(v);
    w.Th[idx] = hi;
    w.Tl[idx] = f2bf(v - bf2f(hi));
}

// ================= fp32 -> hi/lo bf16 conversion =================
__global__ void conv_kernel(const float* __restrict__ in, ushort* __restrict__ oh,
                            ushort* __restrict__ ol, int total4) {
    int i = blockIdx.x * 256 + threadIdx.x;
    if (i >= total4) return;
    float4 v = *(const float4*)(in + (size_t)i * 4);
    ushort4 h, l;
    h.x = f2bf(v.x); l.x = f2bf(v.x - bf2f(h.x));
    h.y = f2bf(v.y); l.y = f2bf(v.y - bf2f(h.y));
    h.z = f2bf(v.z); l.z = f2bf(v.z - bf2f(h.z));
    h.w = f2bf(v.w); l.w = f2bf(v.w - bf2f(h.w));
    *(ushort4*)(oh + (size_t)i * 4) = h;
    *(ushort4*)(ol + (size_t)i * 4) = l;
}

// ================= CSR build =================
__global__ void hist_kernel(const int* __restrict__ dst, int* __restrict__ deg) {
    int e = blockIdx.x * blockDim.x + threadIdx.x;
    if (e >= EP) return;
    int d = (e < EE) ? dst[e] : (e - EE);
    atomicAdd(&deg[d], 1);
}

__global__ void bsum_kernel(const int* __restrict__ deg, int* __restrict__ bsum) {
    __shared__ int wsum[4];
    int i = blockIdx.x * 256 + threadIdx.x;
    int v = (i < NN) ? deg[i] : 0;
#pragma unroll
    for (int off = 32; off; off >>= 1) v += __shfl_xor(v, off);
    if ((threadIdx.x & 63) == 0) wsum[threadIdx.x >> 6] = v;
    __syncthreads();
    if (threadIdx.x == 0) bsum[blockIdx.x] = wsum[0] + wsum[1] + wsum[2] + wsum[3];
}

__global__ void bscan_kernel(const int* __restrict__ bsum, int* __restrict__ boff,
                             int* __restrict__ row_last, int nb) {
    int lane = threadIdx.x;  // 64 threads, 1 block
    int carry = 0;
    for (int base = 0; base < nb; base += 64) {
        int i = base + lane;
        int v = (i < nb) ? bsum[i] : 0;
        int x = v;
#pragma unroll
        for (int off = 1; off < 64; off <<= 1) {
            int y = __shfl_up(x, off);
            if (lane >= off) x += y;
        }
        if (i < nb) boff[i] = carry + x - v;
        carry += __shfl(x, 63);
    }
    if (lane == 0) *row_last = carry;
}

__global__ void blockscan_kernel(const int* __restrict__ deg, const int* __restrict__ boff,
                                 int* __restrict__ row_ptr, int* __restrict__ wptr) {
    __shared__ int wsum[4];
    int i = blockIdx.x * 256 + threadIdx.x;
    int v = (i < NN) ? deg[i] : 0;
    int lane = threadIdx.x & 63, w = threadIdx.x >> 6;
    int x = v;
#pragma unroll
    for (int off = 1; off < 64; off <<= 1) {
        int y = __shfl_up(x, off);
        if (lane >= off) x += y;
    }
    if (lane == 63) wsum[w] = x;
    __syncthreads();
    int wo = 0;
    for (int j = 0; j < w; j++) wo += wsum[j];
    if (i < NN) {
        int excl = boff[blockIdx.x] + wo + x - v;
        row_ptr[i] = excl;
        wptr[i] = excl;
    }
}

__global__ void scatter_kernel(const int* __restrict__ src, const int* __restrict__ dst,
                               int* __restrict__ wptr, int* __restrict__ col) {
    int e = blockIdx.x * blockDim.x + threadIdx.x;
    if (e >= EP) return;
    int s, d;
    if (e < EE) { s = src[e]; d = dst[e]; } else { s = d = e - EE; }
    int pos = atomicAdd(&wptr[d], 1);
    col[pos] = s;
}

// ================= fused GATv2 edge phase =================
// xlr is f16: row = node, cols 0..255 = xl, 256..511 = xr.
// One wave per node as 4 groups of 16 lanes; 4 edges per iteration.
// Score: packed f16 + fdot2 into f32. Aggregate: packed f16 hfma2
// (softmax stats m/ssum stay f32; rescale factors f32->f16 splat).
// lrelu(x) = 0.6x + 0.4|x| (exact for slope 0.2).
__global__ __launch_bounds__(256) void gat_fused(const __half* __restrict__ xlr,
                                                 const int* __restrict__ row_ptr,
                                                 const int* __restrict__ col,
                                                 const float* __restrict__ att,
                                                 const float* __restrict__ bias,
                                                 ushort* __restrict__ outH,
                                                 ushort* __restrict__ outL) {
    int wid = blockIdx.x * 4 + (threadIdx.x >> 6);
    if (wid >= NN) return;
    const int lane = threadIdx.x & 63;
    const int g = lane >> 4, sl = lane & 15;
    const int start = row_ptr[wid], end = row_ptr[wid + 1];

    union U8 { uint4 q[2]; __half2 h[8]; unsigned u[8]; };

    // xr slice (this node), elems sl*16 .. sl*16+15
    U8 xr;
    {
        const uint4* xrp = (const uint4*)(xlr + (size_t)wid * XLR + 256 + sl * 16);
        xr.q[0] = xrp[0]; xr.q[1] = xrp[1];
    }
    // att slice as packed f16
    U8 at;
    {
        const float4* ap = (const float4*)(att + sl * 16);
        float4 a0 = ap[0], a1 = ap[1], a2 = ap[2], a3 = ap[3];
        at.h[0] = __floats2half2_rn(a0.x, a0.y); at.h[1] = __floats2half2_rn(a0.z, a0.w);
        at.h[2] = __floats2half2_rn(a1.x, a1.y); at.h[3] = __floats2half2_rn(a1.z, a1.w);
        at.h[4] = __floats2half2_rn(a2.x, a2.y); at.h[5] = __floats2half2_rn(a2.z, a2.w);
        at.h[6] = __floats2half2_rn(a3.x, a3.y); at.h[7] = __floats2half2_rn(a3.z, a3.w);
    }
    const __half2 c06 = __floats2half2_rn(0.6f, 0.6f);
    const __half2 c04 = __floats2half2_rn(0.4f, 0.4f);

    float m = -1e30f, ssum = 0.f;
    __half2 a2[8];
#pragma unroll
    for (int j = 0; j < 8; j++) a2[j] = __floats2half2_rn(0.f, 0.f);

    for (int e0 = start; e0 < end; e0 += 4) {
        int eg = e0 + g;
        bool valid = eg < end;
        int s = col[valid ? eg : (end - 1)];
        U8 xv;
        {
            const uint4* xp = (const uint4*)(xlr + (size_t)s * XLR + sl * 16);
            xv.q[0] = xp[0]; xv.q[1] = xp[1];
        }
        // score: dot(att, lrelu(xl[src] + xr[dst]))
        float pf = 0.f;
#pragma unroll
        for (int i = 0; i < 8; i++) {
            __half2 s2 = __hadd2(xv.h[i], xr.h[i]);
            union { __half2 h; unsigned u; } ab; ab.h = s2; ab.u &= 0x7fff7fffu;
            __half2 l2 = __hfma2(s2, c06, __hmul2(ab.h, c04));  // lrelu
            pf = __builtin_amdgcn_fdot2(l2, at.h[i], pf, false);
        }
#pragma unroll
        for (int off = 1; off < 16; off <<= 1) pf += __shfl_xor(pf, off);

        if (valid) {
            if (pf <= m) {
                float w = __expf(pf - m);
                ssum += w;
                __half2 w2 = __float2half2_rn(w);
#pragma unroll
                for (int j = 0; j < 8; j++) a2[j] = __hfma2(w2, xv.h[j], a2[j]);
            } else {
                float sc = __expf(m - pf);   // 0 on first edge
                ssum = fmaf(ssum, sc, 1.f);
                __half2 sc2 = __float2half2_rn(sc);
#pragma unroll
                for (int j = 0; j < 8; j++) a2[j] = __hfma2(a2[j], sc2, xv.h[j]);
                m = pf;
            }
        }
    }

    // expand to f32 and merge the 4 groups — butterfly over lane bits 16, 32
    float acc[16];
#pragma unroll
    for (int j = 0; j < 8; j++) {
        float2 f = __half22float2(a2[j]);
        acc[2 * j] = f.x;
        acc[2 * j + 1] = f.y;
    }
#pragma unroll
    for (int off = 16; off <= 32; off <<= 1) {
        float m2 = __shfl_xor(m, off);
        float s2 = __shfl_xor(ssum, off);
        float mn = fmaxf(m, m2);
        float f1 = __expf(m - mn);
        float f2 = __expf(m2 - mn);
        ssum = ssum * f1 + s2 * f2;
#pragma unroll
        for (int j = 0; j < 16; j++)
            acc[j] = acc[j] * f1 + __shfl_xor(acc[j], off) * f2;
        m = mn;
    }

    if (g == 0) {
        float inv = 1.f / ssum;
        const float4* bp = (const float4*)(bias + sl * 16);
        float4 b4[4] = {bp[0], bp[1], bp[2], bp[3]};
        const float* bf = (const float*)b4;
        union { ushort u[16]; uint4 q[2]; } Hh, Ll;
#pragma unroll
        for (int j = 0; j < 16; j++) {
            float o = gelu_exact(fmaf(acc[j], inv, bf[j]));
            ushort h = f2bf(o);
            Hh.u[j] = h;
            Ll.u[j] = f2bf(o - bf2f(h));
        }
        size_t ob = (size_t)wid * HH + sl * 16;
        *(uint4*)(outH + ob) = Hh.q[0];
        *(uint4*)(outH + ob + 8) = Hh.q[1];
        *(uint4*)(outL + ob) = Ll.q[0];
        *(uint4*)(outL + ob + 8) = Ll.q[1];
    }
}

// ================= mu/logstd/z + bf16 split of z =================
// muls[MP][128]: cols 0..63 = h@mu_W, 64..127 = h@ls_W (no bias yet)
__global__ void z_kernel(const float* __restrict__ muls,
                         const float* __restrict__ mu_b, const float* __restrict__ ls_b,
                         const float* __restrict__ eps,
                         float* __restrict__ mu, float* __restrict__ lstd,
                         float* __restrict__ z,
                         ushort* __restrict__ zh, ushort* __restrict__ zl) {
    int i = blockIdx.x * 256 + threadIdx.x;
    if (i >= NN * LL) return;
    int row = i >> 6, j = i & 63;
    float mv = muls[(size_t)row * 128 + j] + mu_b[j];
    float lv = fminf(muls[(size_t)row * 128 + 64 + j] + ls_b[j], 10.f);
    float zv = fmaf(eps[i], __expf(lv), mv);
    mu[i] = mv;
    lstd[i] = lv;
    z[i] = zv;
    ushort h = f2bf(zv);
    zh[i] = h;
    zl[i] = f2bf(zv - bf2f(h));
}

extern "C" void kernel_launch(void* const* d_in, const int* in_sizes, int n_in,
                              void* d_out, int out_size, void* d_ws, size_t ws_size,
                              hipStream_t stream) {
    const float* x       = (const float*)d_in[0];
    const int*   ei      = (const int*)d_in[1];
    const float* eps     = (const float*)d_in[2];
    const float* enc_Wl  = (const float*)d_in[3];
    const float* enc_Wr  = (const float*)d_in[4];
    const float* enc_att = (const float*)d_in[5];
    const float* enc_b   = (const float*)d_in[6];
    const float* mu_W    = (const float*)d_in[7];
    const float* mu_b    = (const float*)d_in[8];
    const float* ls_W    = (const float*)d_in[9];
    const float* ls_b    = (const float*)d_in[10];
    const float* dec0_Wl = (const float*)d_in[11];
    const float* dec0_Wr = (const float*)d_in[12];
    const float* dec0_att= (const float*)d_in[13];
    const float* dec0_b  = (const float*)d_in[14];
    const float* dec_Wl  = (const float*)d_in[15];
    const float* dec_Wr  = (const float*)d_in[16];
    const float* dec_att = (const float*)d_in[17];
    const float* dec_b   = (const float*)d_in[18];
    const float* out_W   = (const float*)d_in[19];
    const float* out_b   = (const float*)d_in[20];

    const int* esrc = ei;
    const int* edst = ei + EE;

    float* out_f = (float*)d_out;
    float* xrec = out_f;
    float* z    = out_f + (size_t)NN * DD;
    float* mu   = z + (size_t)NN * LL;
    float* lstd = mu + (size_t)NN * LL;

    // ---- workspace layout ----
    float* wsf = (float*)d_ws;
    __half* xlr = (__half*)wsf;                     // MP*512 f16  (= MP*256 floats)
    float* muls = wsf + (size_t)MP * 256;           // MP*128 f32
    ushort* Ah = (ushort*)(muls + (size_t)MP * 128);// MP*256 bf16
    ushort* Al = Ah + (size_t)MP * 256;
    ushort* Th = Al + (size_t)MP * 256;             // 1,048,576 bf16
    ushort* Tl = Th + 1048576;
    int* deg     = (int*)(Tl + 1048576);
    int* row_ptr = deg + NN;
    int* wptr    = row_ptr + NN + 1;
    int* col     = wptr + NN;
    int* bsum    = col + EP;
    int* boff    = bsum + 256;

    // weight pack: per-layer Wl/Wr pairs CONTIGUOUS so fused Nc=512 GEMM works
    WPack p;
    size_t off = 0;
    int wi = 0;
    auto add = [&](const float* W, int K, int N) {
        p.d[wi] = {W, Th + off, Tl + off, K, N};
        off += (size_t)K * N;
        wi++;
    };
    for (int l = 0; l < 4; l++) {                     // 0..7: enc (Wl,Wr)*4
        add(enc_Wl + (size_t)l * DD * HH, DD, HH);
        add(enc_Wr + (size_t)l * DD * HH, DD, HH);
    }
    add(dec0_Wl, LL, HH);                             // 8,9
    add(dec0_Wr, LL, HH);
    for (int l = 0; l < 3; l++) {                     // 10..15: dec (Wl,Wr)*3
        add(dec_Wl + (size_t)l * HH * HH, HH, HH);
        add(dec_Wr + (size_t)l * HH * HH, HH, HH);
    }
    add(out_W, HH, DD);                               // 16
    add(mu_W, HH, LL);                                // 17,18 contiguous -> Nc=128
    add(ls_W, HH, LL);

    const int eb = (EP + 255) / 256;
    const int nb = (NN + 3) / 4;            // gat: 4 nodes (waves) per block
    const int cb = (NN * 64 + 255) / 256;
    dim3 mmg_pair(4, MP / 128);             // Nc=512 fused Wl|Wr
    dim3 mmg_out(2, MP / 128);              // Nc=256
    dim3 mmg_muls(1, MP / 128);             // Nc=128 fused mu|ls

    // ---- weight conversion + CSR build ----
    wconv_kernel<<<dim3(256, 19), 256, 0, stream>>>(p);
    (void)hipMemsetAsync(deg, 0, (size_t)NN * sizeof(int), stream);
    hist_kernel<<<eb, 256, 0, stream>>>(edst, deg);
    bsum_kernel<<<NB2, 256, 0, stream>>>(deg, bsum);
    bscan_kernel<<<1, 64, 0, stream>>>(bsum, boff, row_ptr + NN, NB2);
    blockscan_kernel<<<NB2, 256, 0, stream>>>(deg, boff, row_ptr, wptr);
    scatter_kernel<<<eb, 256, 0, stream>>>(esrc, edst, wptr, col);

    // ---- x -> hi/lo ----
    conv_kernel<<<cb, 256, 0, stream>>>(x, Ah, Al, NN * 64);

    // ---- encoder ----
    for (int l = 0; l < 4; l++) {
        mm_bf16<1><<<mmg_pair, 256, 0, stream>>>(Ah, Al, p.d[2 * l].Th, p.d[2 * l].Tl,
                                                 nullptr, xlr, NN, DD, XLR);
        gat_fused<<<nb, 256, 0, stream>>>(xlr, row_ptr, col,
                                          enc_att + (size_t)l * HH,
                                          enc_b + (size_t)l * HH, Ah, Al);
    }

    // ---- mu / logstd / z (fused Nc=128 GEMM) ----
    mm_bf16<0><<<mmg_muls, 256, 0, stream>>>(Ah, Al, p.d[17].Th, p.d[17].Tl, nullptr,
                                             muls, NN, HH, 128);
    z_kernel<<<(NN * LL + 255) / 256, 256, 0, stream>>>(muls, mu_b, ls_b, eps,
                                                        mu, lstd, z, Ah, Al);

    // ---- decoder ----
    for (int l = 0; l < 4; l++) {
        const ushort *BH, *BL;
        const float *at, *bb;
        int K;
        if (l == 0) {
            BH = p.d[8].Th; BL = p.d[8].Tl;      // dec0 Wl|Wr combined [512][64]
            at = dec0_att; bb = dec0_b; K = LL;
        } else {
            BH = p.d[10 + 2 * (l - 1)].Th; BL = p.d[10 + 2 * (l - 1)].Tl;
            at = dec_att + (size_t)(l - 1) * HH;
            bb = dec_b + (size_t)(l - 1) * HH;
            K = HH;
        }
        mm_bf16<1><<<mmg_pair, 256, 0, stream>>>(Ah, Al, BH, BL, nullptr, xlr, NN, K, XLR);
        gat_fused<<<nb, 256, 0, stream>>>(xlr, row_ptr, col, at, bb, Ah, Al);
    }

    // ---- output projection ----
    mm_bf16<0><<<mmg_out, 256, 0, stream>>>(Ah, Al, p.d[16].Th, p.d[16].Tl, out_b,
                                            xrec, NN, HH, DD);
}

// Round 8
// 1338.328 us; speedup vs baseline: 3.2167x; 1.1197x over previous
//
#include <hip/hip_runtime.h>
#include <hip/hip_fp16.h>
#include <math.h>

#define NN 50000
#define EE 800000
#define DD 256
#define HH 256
#define LL 64
#define EP (EE + NN)          // edges + self loops
#define MP 50048              // 391 * 128, padded row count
#define NB2 ((NN + 255) / 256)
#define XLR 512               // fused xl|xr row stride (f16)

typedef __attribute__((ext_vector_type(8))) short short8;
typedef __attribute__((ext_vector_type(4))) float f32x4;

__device__ __forceinline__ float gelu_exact(float x) {
    return 0.5f * x * (1.f + erff(x * 0.70710678118654752f));
}
__device__ __forceinline__ ushort f2bf(float x) {
    union { float f; unsigned u; } v; v.f = x;
    unsigned r = v.u + 0x7fff + ((v.u >> 16) & 1);
    return (ushort)(r >> 16);
}
__device__ __forceinline__ float bf2f(ushort h) {
    union { float f; unsigned u; } v; v.u = ((unsigned)h) << 16;
    return v.f;
}

// ================= split-bf16 MFMA GEMM (R6 reg-staged, padded LDS) =======
// C[M,Nc] = A[M,K] @ B^T + bias, A hi/lo bf16 [MP][K], B [Nc][K] hi/lo.
// Tile 128x128, BK=32, 4 waves (2x2), per wave 4x4 frags of 16x16x32.
// OM=0: C float; OM=1: C __half (xlr buffer for the GAT gather).
template <int OM>
__global__ __launch_bounds__(256) void mm_bf16(const ushort* __restrict__ Ah,
                                               const ushort* __restrict__ Al,
                                               const ushort* __restrict__ Bh,
                                               const ushort* __restrict__ Bl,
                                               const float* __restrict__ bias,
                                               void* __restrict__ Cout,
                                               int M, int K, int Nc) {
    __shared__ ushort As_h[128][40];
    __shared__ ushort As_l[128][40];
    __shared__ ushort Bs_h[128][40];
    __shared__ ushort Bs_l[128][40];
    const int tid = threadIdx.x;
    const int lane = tid & 63;
    const int wid = tid >> 6;
    const int wr = wid >> 1, wc = wid & 1;
    const int row0 = blockIdx.y * 128;
    const int col0 = blockIdx.x * 128;
    const int srow = tid >> 2;       // 0..63
    const int sk = (tid & 3) << 3;   // 0,8,16,24
    const int fr = lane & 15;
    const int kg = (lane >> 4) << 3; // 0,8,16,24

    f32x4 acc[4][4] = {};

    for (int k0 = 0; k0 < K; k0 += 32) {
#pragma unroll
        for (int h = 0; h < 2; h++) {
            int r = srow + h * 64;
            size_t ga = (size_t)(row0 + r) * K + k0 + sk;
            *(int4*)(&As_h[r][sk]) = *(const int4*)(Ah + ga);
            *(int4*)(&As_l[r][sk]) = *(const int4*)(Al + ga);
            int c = col0 + r;
            int4 bh4 = {0, 0, 0, 0}, bl4 = {0, 0, 0, 0};
            if (c < Nc) {
                size_t gb = (size_t)c * K + k0 + sk;
                bh4 = *(const int4*)(Bh + gb);
                bl4 = *(const int4*)(Bl + gb);
            }
            *(int4*)(&Bs_h[r][sk]) = bh4;
            *(int4*)(&Bs_l[r][sk]) = bl4;
        }
        __syncthreads();
        short8 ah[4], al[4], bh[4], bl[4];
#pragma unroll
        for (int m = 0; m < 4; m++) {
            ah[m] = *(const short8*)&As_h[wr * 64 + m * 16 + fr][kg];
            al[m] = *(const short8*)&As_l[wr * 64 + m * 16 + fr][kg];
        }
#pragma unroll
        for (int n = 0; n < 4; n++) {
            bh[n] = *(const short8*)&Bs_h[wc * 64 + n * 16 + fr][kg];
            bl[n] = *(const short8*)&Bs_l[wc * 64 + n * 16 + fr][kg];
        }
#pragma unroll
        for (int m = 0; m < 4; m++)
#pragma unroll
            for (int n = 0; n < 4; n++) {
                acc[m][n] = __builtin_amdgcn_mfma_f32_16x16x32_bf16(ah[m], bh[n], acc[m][n], 0, 0, 0);
                acc[m][n] = __builtin_amdgcn_mfma_f32_16x16x32_bf16(ah[m], bl[n], acc[m][n], 0, 0, 0);
                acc[m][n] = __builtin_amdgcn_mfma_f32_16x16x32_bf16(al[m], bh[n], acc[m][n], 0, 0, 0);
            }
        __syncthreads();
    }
    // C/D layout: col = lane&15, row = (lane>>4)*4 + r
#pragma unroll
    for (int m = 0; m < 4; m++) {
        int rbase = row0 + wr * 64 + m * 16 + (lane >> 4) * 4;
#pragma unroll
        for (int n = 0; n < 4; n++) {
            int c = col0 + wc * 64 + n * 16 + fr;
            if (c < Nc) {
                float bv = bias ? bias[c] : 0.f;
#pragma unroll
                for (int r = 0; r < 4; r++) {
                    int rr = rbase + r;
                    if (rr < M) {
                        float v = acc[m][n][r] + bv;
                        if (OM == 0)
                            ((float*)Cout)[(size_t)rr * Nc + c] = v;
                        else
                            ((__half*)Cout)[(size_t)rr * Nc + c] = __float2half_rn(v);
                    }
                }
            }
        }
    }
}

// ================= weight transpose + hi/lo split =================
struct WDesc { const float* W; ushort* Th; ushort* Tl; int K; int N; };
struct WPack { WDesc d[19]; };

__global__ void wconv_kernel(WPack p) {
    WDesc w = p.d[blockIdx.y];
    int idx = blockIdx.x * 256 + threadIdx.x;
    int total = w.K * w.N;
    if (idx >= total) return;
    int n = idx / w.K, k = idx - n * w.K;
    float v = w.W[(size_t)k * w.N + n];
    ushort hi = f2bf(v);
    w.Th[idx] = hi;
    w.Tl[idx] = f2bf(v - bf2f(hi));
}

// ================= fp32 -> hi/lo bf16 conversion =================
__global__ void conv_kernel(const float* __restrict__ in, ushort* __restrict__ oh,
                            ushort* __restrict__ ol, int total4) {
    int i = blockIdx.x * 256 + threadIdx.x;
    if (i >= total4) return;
    float4 v = *(const float4*)(in + (size_t)i * 4);
    ushort4 h, l;
    h.x = f2bf(v.x); l.x = f2bf(v.x - bf2f(h.x));
    h.y = f2bf(v.y); l.y = f2bf(v.y - bf2f(h.y));
    h.z = f2bf(v.z); l.z = f2bf(v.z - bf2f(h.z));
    h.w = f2bf(v.w); l.w = f2bf(v.w - bf2f(h.w));
    *(ushort4*)(oh + (size_t)i * 4) = h;
    *(ushort4*)(ol + (size_t)i * 4) = l;
}

// ================= CSR build =================
__global__ void hist_kernel(const int* __restrict__ dst, int* __restrict__ deg) {
    int e = blockIdx.x * blockDim.x + threadIdx.x;
    if (e >= EP) return;
    int d = (e < EE) ? dst[e] : (e - EE);
    atomicAdd(&deg[d], 1);
}

__global__ void bsum_kernel(const int* __restrict__ deg, int* __restrict__ bsum) {
    __shared__ int wsum[4];
    int i = blockIdx.x * 256 + threadIdx.x;
    int v = (i < NN) ? deg[i] : 0;
#pragma unroll
    for (int off = 32; off; off >>= 1) v += __shfl_xor(v, off);
    if ((threadIdx.x & 63) == 0) wsum[threadIdx.x >> 6] = v;
    __syncthreads();
    if (threadIdx.x == 0) bsum[blockIdx.x] = wsum[0] + wsum[1] + wsum[2] + wsum[3];
}

__global__ void bscan_kernel(const int* __restrict__ bsum, int* __restrict__ boff,
                             int* __restrict__ row_last, int nb) {
    int lane = threadIdx.x;  // 64 threads, 1 block
    int carry = 0;
    for (int base = 0; base < nb; base += 64) {
        int i = base + lane;
        int v = (i < nb) ? bsum[i] : 0;
        int x = v;
#pragma unroll
        for (int off = 1; off < 64; off <<= 1) {
            int y = __shfl_up(x, off);
            if (lane >= off) x += y;
        }
        if (i < nb) boff[i] = carry + x - v;
        carry += __shfl(x, 63);
    }
    if (lane == 0) *row_last = carry;
}

__global__ void blockscan_kernel(const int* __restrict__ deg, const int* __restrict__ boff,
                                 int* __restrict__ row_ptr, int* __restrict__ wptr) {
    __shared__ int wsum[4];
    int i = blockIdx.x * 256 + threadIdx.x;
    int v = (i < NN) ? deg[i] : 0;
    int lane = threadIdx.x & 63, w = threadIdx.x >> 6;
    int x = v;
#pragma unroll
    for (int off = 1; off < 64; off <<= 1) {
        int y = __shfl_up(x, off);
        if (lane >= off) x += y;
    }
    if (lane == 63) wsum[w] = x;
    __syncthreads();
    int wo = 0;
    for (int j = 0; j < w; j++) wo += wsum[j];
    if (i < NN) {
        int excl = boff[blockIdx.x] + wo + x - v;
        row_ptr[i] = excl;
        wptr[i] = excl;
    }
}

__global__ void scatter_kernel(const int* __restrict__ src, const int* __restrict__ dst,
                               int* __restrict__ wptr, int* __restrict__ col) {
    int e = blockIdx.x * blockDim.x + threadIdx.x;
    if (e >= EP) return;
    int s, d;
    if (e < EE) { s = src[e]; d = dst[e]; } else { s = d = e - EE; }
    int pos = atomicAdd(&wptr[d], 1);
    col[pos] = s;
}

// ================= fused GATv2 edge phase =================
// xlr f16: row = node, cols 0..255 = xl, 256..511 = xr.
// One wave per node as 4 groups of 16 lanes; 4 edges per iteration.
// Branch-free online softmax (invalid edges masked with -inf score).
// Register double-buffer: next iteration's 4 rows prefetched before compute.
// Epilogue distributed over all 64 lanes (4 gelu each).
__global__ __launch_bounds__(256) void gat_fused(const __half* __restrict__ xlr,
                                                 const int* __restrict__ row_ptr,
                                                 const int* __restrict__ col,
                                                 const float* __restrict__ att,
                                                 const float* __restrict__ bias,
                                                 ushort* __restrict__ outH,
                                                 ushort* __restrict__ outL) {
    int wid = blockIdx.x * 4 + (threadIdx.x >> 6);
    if (wid >= NN) return;
    const int lane = threadIdx.x & 63;
    const int g = lane >> 4, sl = lane & 15;
    const int start = row_ptr[wid], end = row_ptr[wid + 1];

    union U8 { uint4 q[2]; __half2 h[8]; };

    // xr slice (this node), elems sl*16 .. sl*16+15
    U8 xr;
    {
        const uint4* xrp = (const uint4*)(xlr + (size_t)wid * XLR + 256 + sl * 16);
        xr.q[0] = xrp[0]; xr.q[1] = xrp[1];
    }
    // att slice as packed f16
    U8 at;
    {
        const float4* ap = (const float4*)(att + sl * 16);
        float4 a0 = ap[0], a1 = ap[1], a2_ = ap[2], a3 = ap[3];
        at.h[0] = __floats2half2_rn(a0.x, a0.y); at.h[1] = __floats2half2_rn(a0.z, a0.w);
        at.h[2] = __floats2half2_rn(a1.x, a1.y); at.h[3] = __floats2half2_rn(a1.z, a1.w);
        at.h[4] = __floats2half2_rn(a2_.x, a2_.y); at.h[5] = __floats2half2_rn(a2_.z, a2_.w);
        at.h[6] = __floats2half2_rn(a3.x, a3.y); at.h[7] = __floats2half2_rn(a3.z, a3.w);
    }
    const __half2 c06 = __floats2half2_rn(0.6f, 0.6f);
    const __half2 c04 = __floats2half2_rn(0.4f, 0.4f);

    float m = -1e30f, ssum = 0.f;
    __half2 a2[8];
#pragma unroll
    for (int j = 0; j < 8; j++) a2[j] = __floats2half2_rn(0.f, 0.f);

    // prologue: load first edge row for this group
    int eg = start + g;
    bool vc = eg < end;
    int sc = col[vc ? eg : (end - 1)];
    U8 xc;
    {
        const uint4* xp = (const uint4*)(xlr + (size_t)sc * XLR + sl * 16);
        xc.q[0] = xp[0]; xc.q[1] = xp[1];
    }

    for (int e0 = start; e0 < end; e0 += 4) {
        // ---- prefetch next iteration's row (issues before compute) ----
        int egn = e0 + 4 + g;
        bool vn = egn < end;
        int sn = col[vn ? egn : (end - 1)];
        U8 xn;
        {
            const uint4* xp = (const uint4*)(xlr + (size_t)sn * XLR + sl * 16);
            xn.q[0] = xp[0]; xn.q[1] = xp[1];
        }

        // ---- score: dot(att, lrelu(xc + xr)), lrelu = 0.6x + 0.4|x| ----
        float pf = 0.f;
#pragma unroll
        for (int i = 0; i < 8; i++) {
            __half2 s2 = __hadd2(xc.h[i], xr.h[i]);
            union { __half2 h; unsigned u; } ab; ab.h = s2; ab.u &= 0x7fff7fffu;
            __half2 l2 = __hfma2(s2, c06, __hmul2(ab.h, c04));
            pf = __builtin_amdgcn_fdot2(l2, at.h[i], pf, false);
        }
#pragma unroll
        for (int off = 1; off < 16; off <<= 1) pf += __shfl_xor(pf, off);
        pf = vc ? pf : -INFINITY;

        // ---- branch-free online softmax update ----
        float mn = fmaxf(m, pf);
        float f = __expf(m - mn);
        float w = __expf(pf - mn);
        ssum = fmaf(ssum, f, w);
        __half2 f2 = __float2half2_rn(f);
        __half2 w2 = __float2half2_rn(w);
#pragma unroll
        for (int j = 0; j < 8; j++) a2[j] = __hfma2(a2[j], f2, __hmul2(xc.h[j], w2));
        m = mn;

        xc = xn; vc = vn;
    }

    // ---- merge m/ssum across the 4 groups ----
    float m_all = m;
#pragma unroll
    for (int off = 16; off <= 32; off <<= 1) m_all = fmaxf(m_all, __shfl_xor(m_all, off));
    float fg = __expf(m - m_all);   // per-group rescale (0 for empty groups)
    ssum *= fg;
#pragma unroll
    for (int off = 16; off <= 32; off <<= 1) ssum += __shfl_xor(ssum, off);

    // ---- scale own acc by fg, butterfly-add across groups ----
    float acc[16];
#pragma unroll
    for (int j = 0; j < 8; j++) {
        float2 fv = __half22float2(a2[j]);
        acc[2 * j] = fv.x * fg;
        acc[2 * j + 1] = fv.y * fg;
    }
#pragma unroll
    for (int off = 16; off <= 32; off <<= 1) {
#pragma unroll
        for (int j = 0; j < 16; j++) acc[j] += __shfl_xor(acc[j], off);
    }

    // ---- distributed epilogue: lane (g,sl) handles elems sl*16 + 4g .. +3 ----
    float inv = 1.f / ssum;
    float4 b4 = *(const float4*)(bias + sl * 16 + 4 * g);
    const float* bf = (const float*)&b4;
    ushort4 hh, ll;
    {
        ushort* hu = (ushort*)&hh;
        ushort* lu = (ushort*)&ll;
#pragma unroll
        for (int jj = 0; jj < 4; jj++) {
            // compile-time-indexed select of acc[4g+jj]
            float v0 = acc[jj], v1 = acc[4 + jj], v2 = acc[8 + jj], v3 = acc[12 + jj];
            float v = (g == 0) ? v0 : (g == 1) ? v1 : (g == 2) ? v2 : v3;
            float o = gelu_exact(fmaf(v, inv, bf[jj]));
            ushort h = f2bf(o);
            hu[jj] = h;
            lu[jj] = f2bf(o - bf2f(h));
        }
    }
    size_t ob = (size_t)wid * HH + sl * 16 + 4 * g;
    *(ushort4*)(outH + ob) = hh;
    *(ushort4*)(outL + ob) = ll;
}

// ================= mu/logstd/z + bf16 split of z =================
// muls[MP][128]: cols 0..63 = h@mu_W, 64..127 = h@ls_W (no bias yet)
__global__ void z_kernel(const float* __restrict__ muls,
                         const float* __restrict__ mu_b, const float* __restrict__ ls_b,
                         const float* __restrict__ eps,
                         float* __restrict__ mu, float* __restrict__ lstd,
                         float* __restrict__ z,
                         ushort* __restrict__ zh, ushort* __restrict__ zl) {
    int i = blockIdx.x * 256 + threadIdx.x;
    if (i >= NN * LL) return;
    int row = i >> 6, j = i & 63;
    float mv = muls[(size_t)row * 128 + j] + mu_b[j];
    float lv = fminf(muls[(size_t)row * 128 + 64 + j] + ls_b[j], 10.f);
    float zv = fmaf(eps[i], __expf(lv), mv);
    mu[i] = mv;
    lstd[i] = lv;
    z[i] = zv;
    ushort h = f2bf(zv);
    zh[i] = h;
    zl[i] = f2bf(zv - bf2f(h));
}

extern "C" void kernel_launch(void* const* d_in, const int* in_sizes, int n_in,
                              void* d_out, int out_size, void* d_ws, size_t ws_size,
                              hipStream_t stream) {
    const float* x       = (const float*)d_in[0];
    const int*   ei      = (const int*)d_in[1];
    const float* eps     = (const float*)d_in[2];
    const float* enc_Wl  = (const float*)d_in[3];
    const float* enc_Wr  = (const float*)d_in[4];
    const float* enc_att = (const float*)d_in[5];
    const float* enc_b   = (const float*)d_in[6];
    const float* mu_W    = (const float*)d_in[7];
    const float* mu_b    = (const float*)d_in[8];
    const float* ls_W    = (const float*)d_in[9];
    const float* ls_b    = (const float*)d_in[10];
    const float* dec0_Wl = (const float*)d_in[11];
    const float* dec0_Wr = (const float*)d_in[12];
    const float* dec0_att= (const float*)d_in[13];
    const float* dec0_b  = (const float*)d_in[14];
    const float* dec_Wl  = (const float*)d_in[15];
    const float* dec_Wr  = (const float*)d_in[16];
    const float* dec_att = (const float*)d_in[17];
    const float* dec_b   = (const float*)d_in[18];
    const float* out_W   = (const float*)d_in[19];
    const float* out_b   = (const float*)d_in[20];

    const int* esrc = ei;
    const int* edst = ei + EE;

    float* out_f = (float*)d_out;
    float* xrec = out_f;
    float* z    = out_f + (size_t)NN * DD;
    float* mu   = z + (size_t)NN * LL;
    float* lstd = mu + (size_t)NN * LL;

    // ---- workspace layout ----
    float* wsf = (float*)d_ws;
    __half* xlr = (__half*)wsf;                     // MP*512 f16  (= MP*256 floats)
    float* muls = wsf + (size_t)MP * 256;           // MP*128 f32
    ushort* Ah = (ushort*)(muls + (size_t)MP * 128);// MP*256 bf16
    ushort* Al = Ah + (size_t)MP * 256;
    ushort* Th = Al + (size_t)MP * 256;             // 1,048,576 bf16
    ushort* Tl = Th + 1048576;
    int* deg     = (int*)(Tl + 1048576);
    int* row_ptr = deg + NN;
    int* wptr    = row_ptr + NN + 1;
    int* col     = wptr + NN;
    int* bsum    = col + EP;
    int* boff    = bsum + 256;

    // weight pack: per-layer Wl/Wr pairs CONTIGUOUS so fused Nc=512 GEMM works
    WPack p;
    size_t off = 0;
    int wi = 0;
    auto add = [&](const float* W, int K, int N) {
        p.d[wi] = {W, Th + off, Tl + off, K, N};
        off += (size_t)K * N;
        wi++;
    };
    for (int l = 0; l < 4; l++) {                     // 0..7: enc (Wl,Wr)*4
        add(enc_Wl + (size_t)l * DD * HH, DD, HH);
        add(enc_Wr + (size_t)l * DD * HH, DD, HH);
    }
    add(dec0_Wl, LL, HH);                             // 8,9
    add(dec0_Wr, LL, HH);
    for (int l = 0; l < 3; l++) {                     // 10..15: dec (Wl,Wr)*3
        add(dec_Wl + (size_t)l * HH * HH, HH, HH);
        add(dec_Wr + (size_t)l * HH * HH, HH, HH);
    }
    add(out_W, HH, DD);                               // 16
    add(mu_W, HH, LL);                                // 17,18 contiguous -> Nc=128
    add(ls_W, HH, LL);

    const int eb = (EP + 255) / 256;
    const int nb = (NN + 3) / 4;            // gat: 4 nodes (waves) per block
    const int cb = (NN * 64 + 255) / 256;
    dim3 mmg_pair(4, MP / 128);             // Nc=512 fused Wl|Wr
    dim3 mmg_out(2, MP / 128);              // Nc=256
    dim3 mmg_muls(1, MP / 128);             // Nc=128 fused mu|ls

    // ---- weight conversion + CSR build ----
    wconv_kernel<<<dim3(256, 19), 256, 0, stream>>>(p);
    (void)hipMemsetAsync(deg, 0, (size_t)NN * sizeof(int), stream);
    hist_kernel<<<eb, 256, 0, stream>>>(edst, deg);
    bsum_kernel<<<NB2, 256, 0, stream>>>(deg, bsum);
    bscan_kernel<<<1, 64, 0, stream>>>(bsum, boff, row_ptr + NN, NB2);
    blockscan_kernel<<<NB2, 256, 0, stream>>>(deg, boff, row_ptr, wptr);
    scatter_kernel<<<eb, 256, 0, stream>>>(esrc, edst, wptr, col);

    // ---- x -> hi/lo ----
    conv_kernel<<<cb, 256, 0, stream>>>(x, Ah, Al, NN * 64);

    // ---- encoder ----
    for (int l = 0; l < 4; l++) {
        mm_bf16<1><<<mmg_pair, 256, 0, stream>>>(Ah, Al, p.d[2 * l].Th, p.d[2 * l].Tl,
                                                 nullptr, xlr, NN, DD, XLR);
        gat_fused<<<nb, 256, 0, stream>>>(xlr, row_ptr, col,
                                          enc_att + (size_t)l * HH,
                                          enc_b + (size_t)l * HH, Ah, Al);
    }

    // ---- mu / logstd / z (fused Nc=128 GEMM) ----
    mm_bf16<0><<<mmg_muls, 256, 0, stream>>>(Ah, Al, p.d[17].Th, p.d[17].Tl, nullptr,
                                             muls, NN, HH, 128);
    z_kernel<<<(NN * LL + 255) / 256, 256, 0, stream>>>(muls, mu_b, ls_b, eps,
                                                        mu, lstd, z, Ah, Al);

    // ---- decoder ----
    for (int l = 0; l < 4; l++) {
        const ushort *BH, *BL;
        const float *at, *bb;
        int K;
        if (l == 0) {
            BH = p.d[8].Th; BL = p.d[8].Tl;      // dec0 Wl|Wr combined [512][64]
            at = dec0_att; bb = dec0_b; K = LL;
        } else {
            BH = p.d[10 + 2 * (l - 1)].Th; BL = p.d[10 + 2 * (l - 1)].Tl;
            at = dec_att + (size_t)(l - 1) * HH;
            bb = dec_b + (size_t)(l - 1) * HH;
            K = HH;
        }
        mm_bf16<1><<<mmg_pair, 256, 0, stream>>>(Ah, Al, BH, BL, nullptr, xlr, NN, K, XLR);
        gat_fused<<<nb, 256, 0, stream>>>(xlr, row_ptr, col, at, bb, Ah, Al);
    }

    // ---- output projection ----
    mm_bf16<0><<<mmg_out, 256, 0, stream>>>(Ah, Al, p.d[16].Th, p.d[16].Tl, out_b,
                                            xrec, NN, HH, DD);
}

// Round 9
// 1190.499 us; speedup vs baseline: 3.6162x; 1.1242x over previous
//
#include <hip/hip_runtime.h>
#include <hip/hip_fp16.h>
#include <math.h>

#define NN 50000
#define EE 800000
#define DD 256
#define HH 256
#define LL 64
#define EP (EE + NN)          // edges + self loops
#define MP 50048              // 391 * 128, padded row count
#define NB2 ((NN + 255) / 256)
#define XLR 512               // fused xl|xr row stride (f16)

typedef __attribute__((ext_vector_type(8))) _Float16 half8;
typedef __attribute__((ext_vector_type(4))) float f32x4;

__device__ __forceinline__ float gelu_exact(float x) {
    return 0.5f * x * (1.f + erff(x * 0.70710678118654752f));
}
__device__ __forceinline__ ushort f2h(float x) {
    return __half_as_ushort(__float2half_rn(x));
}
__device__ __forceinline__ float h2f(ushort u) {
    return __half2float(__ushort_as_half(u));
}

// ================= f16 MFMA GEMM: A f16, B split-f16 (hi+lo) ==============
// C[M,Nc] = A[M,K] @ B^T + bias, A f16 [MP][K], B [Nc][K] as hi/lo f16.
// B hi+lo makes weights effectively exact; error = A's f16 rounding only.
// Tile 128x128, BK=32, 4 waves (2x2), per wave 4x4 frags of 16x16x32.
// 2 MFMAs per frag-pair (vs 3 for split-bf16), 3 LDS arrays (vs 4), 30KB.
// OM=0: C float; OM=1: C __half (xlr buffer for the GAT gather).
template <int OM>
__global__ __launch_bounds__(256) void mm_f16(const ushort* __restrict__ A,
                                              const ushort* __restrict__ Bh,
                                              const ushort* __restrict__ Bl,
                                              const float* __restrict__ bias,
                                              void* __restrict__ Cout,
                                              int M, int K, int Nc) {
    __shared__ ushort As[128][40];
    __shared__ ushort Bs_h[128][40];
    __shared__ ushort Bs_l[128][40];
    const int tid = threadIdx.x;
    const int lane = tid & 63;
    const int wid = tid >> 6;
    const int wr = wid >> 1, wc = wid & 1;
    const int row0 = blockIdx.y * 128;
    const int col0 = blockIdx.x * 128;
    const int srow = tid >> 2;       // 0..63
    const int sk = (tid & 3) << 3;   // 0,8,16,24
    const int fr = lane & 15;
    const int kg = (lane >> 4) << 3; // 0,8,16,24

    f32x4 acc[4][4] = {};

    for (int k0 = 0; k0 < K; k0 += 32) {
#pragma unroll
        for (int h = 0; h < 2; h++) {
            int r = srow + h * 64;
            size_t ga = (size_t)(row0 + r) * K + k0 + sk;
            *(int4*)(&As[r][sk]) = *(const int4*)(A + ga);
            int c = col0 + r;
            int4 bh4 = {0, 0, 0, 0}, bl4 = {0, 0, 0, 0};
            if (c < Nc) {
                size_t gb = (size_t)c * K + k0 + sk;
                bh4 = *(const int4*)(Bh + gb);
                bl4 = *(const int4*)(Bl + gb);
            }
            *(int4*)(&Bs_h[r][sk]) = bh4;
            *(int4*)(&Bs_l[r][sk]) = bl4;
        }
        __syncthreads();
        half8 a[4], bh[4], bl[4];
#pragma unroll
        for (int m = 0; m < 4; m++)
            a[m] = *(const half8*)&As[wr * 64 + m * 16 + fr][kg];
#pragma unroll
        for (int n = 0; n < 4; n++) {
            bh[n] = *(const half8*)&Bs_h[wc * 64 + n * 16 + fr][kg];
            bl[n] = *(const half8*)&Bs_l[wc * 64 + n * 16 + fr][kg];
        }
#pragma unroll
        for (int m = 0; m < 4; m++)
#pragma unroll
            for (int n = 0; n < 4; n++) {
                acc[m][n] = __builtin_amdgcn_mfma_f32_16x16x32_f16(a[m], bh[n], acc[m][n], 0, 0, 0);
                acc[m][n] = __builtin_amdgcn_mfma_f32_16x16x32_f16(a[m], bl[n], acc[m][n], 0, 0, 0);
            }
        __syncthreads();
    }
    // C/D layout: col = lane&15, row = (lane>>4)*4 + r
#pragma unroll
    for (int m = 0; m < 4; m++) {
        int rbase = row0 + wr * 64 + m * 16 + (lane >> 4) * 4;
#pragma unroll
        for (int n = 0; n < 4; n++) {
            int c = col0 + wc * 64 + n * 16 + fr;
            if (c < Nc) {
                float bv = bias ? bias[c] : 0.f;
#pragma unroll
                for (int r = 0; r < 4; r++) {
                    int rr = rbase + r;
                    if (rr < M) {
                        float v = acc[m][n][r] + bv;
                        if (OM == 0)
                            ((float*)Cout)[(size_t)rr * Nc + c] = v;
                        else
                            ((__half*)Cout)[(size_t)rr * Nc + c] = __float2half_rn(v);
                    }
                }
            }
        }
    }
}

// ================= weight transpose + hi/lo f16 split =================
struct WDesc { const float* W; ushort* Th; ushort* Tl; int K; int N; };
struct WPack { WDesc d[19]; };

__global__ void wconv_kernel(WPack p) {
    WDesc w = p.d[blockIdx.y];
    int idx = blockIdx.x * 256 + threadIdx.x;
    int total = w.K * w.N;
    if (idx >= total) return;
    int n = idx / w.K, k = idx - n * w.K;
    float v = w.W[(size_t)k * w.N + n];
    ushort hi = f2h(v);
    w.Th[idx] = hi;
    w.Tl[idx] = f2h(v - h2f(hi));
}

// ================= fp32 -> f16 conversion =================
__global__ void conv_kernel(const float* __restrict__ in, ushort* __restrict__ o,
                            int total4) {
    int i = blockIdx.x * 256 + threadIdx.x;
    if (i >= total4) return;
    float4 v = *(const float4*)(in + (size_t)i * 4);
    ushort4 h;
    h.x = f2h(v.x); h.y = f2h(v.y); h.z = f2h(v.z); h.w = f2h(v.w);
    *(ushort4*)(o + (size_t)i * 4) = h;
}

// ================= CSR build =================
__global__ void hist_kernel(const int* __restrict__ dst, int* __restrict__ deg) {
    int e = blockIdx.x * blockDim.x + threadIdx.x;
    if (e >= EP) return;
    int d = (e < EE) ? dst[e] : (e - EE);
    atomicAdd(&deg[d], 1);
}

__global__ void bsum_kernel(const int* __restrict__ deg, int* __restrict__ bsum) {
    __shared__ int wsum[4];
    int i = blockIdx.x * 256 + threadIdx.x;
    int v = (i < NN) ? deg[i] : 0;
#pragma unroll
    for (int off = 32; off; off >>= 1) v += __shfl_xor(v, off);
    if ((threadIdx.x & 63) == 0) wsum[threadIdx.x >> 6] = v;
    __syncthreads();
    if (threadIdx.x == 0) bsum[blockIdx.x] = wsum[0] + wsum[1] + wsum[2] + wsum[3];
}

__global__ void bscan_kernel(const int* __restrict__ bsum, int* __restrict__ boff,
                             int* __restrict__ row_last, int nb) {
    int lane = threadIdx.x;  // 64 threads, 1 block
    int carry = 0;
    for (int base = 0; base < nb; base += 64) {
        int i = base + lane;
        int v = (i < nb) ? bsum[i] : 0;
        int x = v;
#pragma unroll
        for (int off = 1; off < 64; off <<= 1) {
            int y = __shfl_up(x, off);
            if (lane >= off) x += y;
        }
        if (i < nb) boff[i] = carry + x - v;
        carry += __shfl(x, 63);
    }
    if (lane == 0) *row_last = carry;
}

__global__ void blockscan_kernel(const int* __restrict__ deg, const int* __restrict__ boff,
                                 int* __restrict__ row_ptr, int* __restrict__ wptr) {
    __shared__ int wsum[4];
    int i = blockIdx.x * 256 + threadIdx.x;
    int v = (i < NN) ? deg[i] : 0;
    int lane = threadIdx.x & 63, w = threadIdx.x >> 6;
    int x = v;
#pragma unroll
    for (int off = 1; off < 64; off <<= 1) {
        int y = __shfl_up(x, off);
        if (lane >= off) x += y;
    }
    if (lane == 63) wsum[w] = x;
    __syncthreads();
    int wo = 0;
    for (int j = 0; j < w; j++) wo += wsum[j];
    if (i < NN) {
        int excl = boff[blockIdx.x] + wo + x - v;
        row_ptr[i] = excl;
        wptr[i] = excl;
    }
}

__global__ void scatter_kernel(const int* __restrict__ src, const int* __restrict__ dst,
                               int* __restrict__ wptr, int* __restrict__ col) {
    int e = blockIdx.x * blockDim.x + threadIdx.x;
    if (e >= EP) return;
    int s, d;
    if (e < EE) { s = src[e]; d = dst[e]; } else { s = d = e - EE; }
    int pos = atomicAdd(&wptr[d], 1);
    col[pos] = s;
}

// ================= fused GATv2 edge phase =================
// xlr f16: row = node, cols 0..255 = xl, 256..511 = xr.
// One wave per node as 4 groups of 16 lanes; 4 edges per iteration.
// Branch-free online softmax; register prefetch; distributed epilogue.
// Output: single f16 array (next GEMM's A).
__global__ __launch_bounds__(256) void gat_fused(const __half* __restrict__ xlr,
                                                 const int* __restrict__ row_ptr,
                                                 const int* __restrict__ col,
                                                 const float* __restrict__ att,
                                                 const float* __restrict__ bias,
                                                 ushort* __restrict__ out) {
    int wid = blockIdx.x * 4 + (threadIdx.x >> 6);
    if (wid >= NN) return;
    const int lane = threadIdx.x & 63;
    const int g = lane >> 4, sl = lane & 15;
    const int start = row_ptr[wid], end = row_ptr[wid + 1];

    union U8 { uint4 q[2]; __half2 h[8]; };

    // xr slice (this node), elems sl*16 .. sl*16+15
    U8 xr;
    {
        const uint4* xrp = (const uint4*)(xlr + (size_t)wid * XLR + 256 + sl * 16);
        xr.q[0] = xrp[0]; xr.q[1] = xrp[1];
    }
    // att slice as packed f16
    U8 at;
    {
        const float4* ap = (const float4*)(att + sl * 16);
        float4 a0 = ap[0], a1 = ap[1], a2_ = ap[2], a3 = ap[3];
        at.h[0] = __floats2half2_rn(a0.x, a0.y); at.h[1] = __floats2half2_rn(a0.z, a0.w);
        at.h[2] = __floats2half2_rn(a1.x, a1.y); at.h[3] = __floats2half2_rn(a1.z, a1.w);
        at.h[4] = __floats2half2_rn(a2_.x, a2_.y); at.h[5] = __floats2half2_rn(a2_.z, a2_.w);
        at.h[6] = __floats2half2_rn(a3.x, a3.y); at.h[7] = __floats2half2_rn(a3.z, a3.w);
    }
    const __half2 c06 = __floats2half2_rn(0.6f, 0.6f);
    const __half2 c04 = __floats2half2_rn(0.4f, 0.4f);

    float m = -1e30f, ssum = 0.f;
    __half2 a2[8];
#pragma unroll
    for (int j = 0; j < 8; j++) a2[j] = __floats2half2_rn(0.f, 0.f);

    // prologue: load first edge row for this group
    int eg = start + g;
    bool vc = eg < end;
    int sc = col[vc ? eg : (end - 1)];
    U8 xc;
    {
        const uint4* xp = (const uint4*)(xlr + (size_t)sc * XLR + sl * 16);
        xc.q[0] = xp[0]; xc.q[1] = xp[1];
    }

    for (int e0 = start; e0 < end; e0 += 4) {
        // ---- prefetch next iteration's row (issues before compute) ----
        int egn = e0 + 4 + g;
        bool vn = egn < end;
        int sn = col[vn ? egn : (end - 1)];
        U8 xn;
        {
            const uint4* xp = (const uint4*)(xlr + (size_t)sn * XLR + sl * 16);
            xn.q[0] = xp[0]; xn.q[1] = xp[1];
        }

        // ---- score: dot(att, lrelu(xc + xr)), lrelu = 0.6x + 0.4|x| ----
        float pf = 0.f;
#pragma unroll
        for (int i = 0; i < 8; i++) {
            __half2 s2 = __hadd2(xc.h[i], xr.h[i]);
            union { __half2 h; unsigned u; } ab; ab.h = s2; ab.u &= 0x7fff7fffu;
            __half2 l2 = __hfma2(s2, c06, __hmul2(ab.h, c04));
            pf = __builtin_amdgcn_fdot2(l2, at.h[i], pf, false);
        }
#pragma unroll
        for (int off = 1; off < 16; off <<= 1) pf += __shfl_xor(pf, off);
        pf = vc ? pf : -INFINITY;

        // ---- branch-free online softmax update ----
        float mn = fmaxf(m, pf);
        float f = __expf(m - mn);
        float w = __expf(pf - mn);
        ssum = fmaf(ssum, f, w);
        __half2 f2 = __float2half2_rn(f);
        __half2 w2 = __float2half2_rn(w);
#pragma unroll
        for (int j = 0; j < 8; j++) a2[j] = __hfma2(a2[j], f2, __hmul2(xc.h[j], w2));
        m = mn;

        xc = xn; vc = vn;
    }

    // ---- merge m/ssum across the 4 groups ----
    float m_all = m;
#pragma unroll
    for (int off = 16; off <= 32; off <<= 1) m_all = fmaxf(m_all, __shfl_xor(m_all, off));
    float fg = __expf(m - m_all);   // per-group rescale (0 for empty groups)
    ssum *= fg;
#pragma unroll
    for (int off = 16; off <= 32; off <<= 1) ssum += __shfl_xor(ssum, off);

    // ---- scale own acc by fg, butterfly-add across groups ----
    float acc[16];
#pragma unroll
    for (int j = 0; j < 8; j++) {
        float2 fv = __half22float2(a2[j]);
        acc[2 * j] = fv.x * fg;
        acc[2 * j + 1] = fv.y * fg;
    }
#pragma unroll
    for (int off = 16; off <= 32; off <<= 1) {
#pragma unroll
        for (int j = 0; j < 16; j++) acc[j] += __shfl_xor(acc[j], off);
    }

    // ---- distributed epilogue: lane (g,sl) handles elems sl*16 + 4g .. +3 ----
    float inv = 1.f / ssum;
    float4 b4 = *(const float4*)(bias + sl * 16 + 4 * g);
    const float* bf = (const float*)&b4;
    ushort4 hh;
    {
        ushort* hu = (ushort*)&hh;
#pragma unroll
        for (int jj = 0; jj < 4; jj++) {
            float v0 = acc[jj], v1 = acc[4 + jj], v2 = acc[8 + jj], v3 = acc[12 + jj];
            float v = (g == 0) ? v0 : (g == 1) ? v1 : (g == 2) ? v2 : v3;
            float o = gelu_exact(fmaf(v, inv, bf[jj]));
            hu[jj] = f2h(o);
        }
    }
    size_t ob = (size_t)wid * HH + sl * 16 + 4 * g;
    *(ushort4*)(out + ob) = hh;
}

// ================= mu/logstd/z + f16 of z =================
// muls[MP][128]: cols 0..63 = h@mu_W, 64..127 = h@ls_W (no bias yet)
__global__ void z_kernel(const float* __restrict__ muls,
                         const float* __restrict__ mu_b, const float* __restrict__ ls_b,
                         const float* __restrict__ eps,
                         float* __restrict__ mu, float* __restrict__ lstd,
                         float* __restrict__ z, ushort* __restrict__ zf) {
    int i = blockIdx.x * 256 + threadIdx.x;
    if (i >= NN * LL) return;
    int row = i >> 6, j = i & 63;
    float mv = muls[(size_t)row * 128 + j] + mu_b[j];
    float lv = fminf(muls[(size_t)row * 128 + 64 + j] + ls_b[j], 10.f);
    float zv = fmaf(eps[i], __expf(lv), mv);
    mu[i] = mv;
    lstd[i] = lv;
    z[i] = zv;
    zf[i] = f2h(zv);
}

extern "C" void kernel_launch(void* const* d_in, const int* in_sizes, int n_in,
                              void* d_out, int out_size, void* d_ws, size_t ws_size,
                              hipStream_t stream) {
    const float* x       = (const float*)d_in[0];
    const int*   ei      = (const int*)d_in[1];
    const float* eps     = (const float*)d_in[2];
    const float* enc_Wl  = (const float*)d_in[3];
    const float* enc_Wr  = (const float*)d_in[4];
    const float* enc_att = (const float*)d_in[5];
    const float* enc_b   = (const float*)d_in[6];
    const float* mu_W    = (const float*)d_in[7];
    const float* mu_b    = (const float*)d_in[8];
    const float* ls_W    = (const float*)d_in[9];
    const float* ls_b    = (const float*)d_in[10];
    const float* dec0_Wl = (const float*)d_in[11];
    const float* dec0_Wr = (const float*)d_in[12];
    const float* dec0_att= (const float*)d_in[13];
    const float* dec0_b  = (const float*)d_in[14];
    const float* dec_Wl  = (const float*)d_in[15];
    const float* dec_Wr  = (const float*)d_in[16];
    const float* dec_att = (const float*)d_in[17];
    const float* dec_b   = (const float*)d_in[18];
    const float* out_W   = (const float*)d_in[19];
    const float* out_b   = (const float*)d_in[20];

    const int* esrc = ei;
    const int* edst = ei + EE;

    float* out_f = (float*)d_out;
    float* xrec = out_f;
    float* z    = out_f + (size_t)NN * DD;
    float* mu   = z + (size_t)NN * LL;
    float* lstd = mu + (size_t)NN * LL;

    // ---- workspace layout ----
    float* wsf = (float*)d_ws;
    __half* xlr = (__half*)wsf;                     // MP*512 f16  (= MP*256 floats)
    float* muls = wsf + (size_t)MP * 256;           // MP*128 f32
    ushort* Af = (ushort*)(muls + (size_t)MP * 128);// MP*256 f16 (GEMM A / gat out)
    ushort* Th = Af + (size_t)MP * 256;             // 1,048,576 f16
    ushort* Tl = Th + 1048576;
    int* deg     = (int*)(Tl + 1048576);
    int* row_ptr = deg + NN;
    int* wptr    = row_ptr + NN + 1;
    int* col     = wptr + NN;
    int* bsum    = col + EP;
    int* boff    = bsum + 256;

    // weight pack: per-layer Wl/Wr pairs CONTIGUOUS so fused Nc=512 GEMM works
    WPack p;
    size_t off = 0;
    int wi = 0;
    auto add = [&](const float* W, int K, int N) {
        p.d[wi] = {W, Th + off, Tl + off, K, N};
        off += (size_t)K * N;
        wi++;
    };
    for (int l = 0; l < 4; l++) {                     // 0..7: enc (Wl,Wr)*4
        add(enc_Wl + (size_t)l * DD * HH, DD, HH);
        add(enc_Wr + (size_t)l * DD * HH, DD, HH);
    }
    add(dec0_Wl, LL, HH);                             // 8,9
    add(dec0_Wr, LL, HH);
    for (int l = 0; l < 3; l++) {                     // 10..15: dec (Wl,Wr)*3
        add(dec_Wl + (size_t)l * HH * HH, HH, HH);
        add(dec_Wr + (size_t)l * HH * HH, HH, HH);
    }
    add(out_W, HH, DD);                               // 16
    add(mu_W, HH, LL);                                // 17,18 contiguous -> Nc=128
    add(ls_W, HH, LL);

    const int eb = (EP + 255) / 256;
    const int nb = (NN + 3) / 4;            // gat: 4 nodes (waves) per block
    const int cb = (NN * 64 + 255) / 256;
    dim3 mmg_pair(4, MP / 128);             // Nc=512 fused Wl|Wr
    dim3 mmg_out(2, MP / 128);              // Nc=256
    dim3 mmg_muls(1, MP / 128);             // Nc=128 fused mu|ls

    // ---- weight conversion + CSR build ----
    wconv_kernel<<<dim3(256, 19), 256, 0, stream>>>(p);
    (void)hipMemsetAsync(deg, 0, (size_t)NN * sizeof(int), stream);
    hist_kernel<<<eb, 256, 0, stream>>>(edst, deg);
    bsum_kernel<<<NB2, 256, 0, stream>>>(deg, bsum);
    bscan_kernel<<<1, 64, 0, stream>>>(bsum, boff, row_ptr + NN, NB2);
    blockscan_kernel<<<NB2, 256, 0, stream>>>(deg, boff, row_ptr, wptr);
    scatter_kernel<<<eb, 256, 0, stream>>>(esrc, edst, wptr, col);

    // ---- x -> f16 ----
    conv_kernel<<<cb, 256, 0, stream>>>(x, Af, NN * 64);

    // ---- encoder ----
    for (int l = 0; l < 4; l++) {
        mm_f16<1><<<mmg_pair, 256, 0, stream>>>(Af, p.d[2 * l].Th, p.d[2 * l].Tl,
                                                nullptr, xlr, NN, DD, XLR);
        gat_fused<<<nb, 256, 0, stream>>>(xlr, row_ptr, col,
                                          enc_att + (size_t)l * HH,
                                          enc_b + (size_t)l * HH, Af);
    }

    // ---- mu / logstd / z (fused Nc=128 GEMM) ----
    mm_f16<0><<<mmg_muls, 256, 0, stream>>>(Af, p.d[17].Th, p.d[17].Tl, nullptr,
                                            muls, NN, HH, 128);
    z_kernel<<<(NN * LL + 255) / 256, 256, 0, stream>>>(muls, mu_b, ls_b, eps,
                                                        mu, lstd, z, Af);

    // ---- decoder ----
    for (int l = 0; l < 4; l++) {
        const ushort *BH, *BL;
        const float *at, *bb;
        int K;
        if (l == 0) {
            BH = p.d[8].Th; BL = p.d[8].Tl;      // dec0 Wl|Wr combined [512][64]
            at = dec0_att; bb = dec0_b; K = LL;
        } else {
            BH = p.d[10 + 2 * (l - 1)].Th; BL = p.d[10 + 2 * (l - 1)].Tl;
            at = dec_att + (size_t)(l - 1) * HH;
            bb = dec_b + (size_t)(l - 1) * HH;
            K = HH;
        }
        mm_f16<1><<<mmg_pair, 256, 0, stream>>>(Af, BH, BL, nullptr, xlr, NN, K, XLR);
        gat_fused<<<nb, 256, 0, stream>>>(xlr, row_ptr, col, at, bb, Af);
    }

    // ---- output projection ----
    mm_f16<0><<<mmg_out, 256, 0, stream>>>(Af, p.d[16].Th, p.d[16].Tl, out_b,
                                           xrec, NN, HH, DD);
}